// Round 8
// baseline (542.751 us; speedup 1.0000x reference)
//
#include <hip/hip_runtime.h>
#include <math.h>

typedef unsigned short ushort;
typedef unsigned int uint;
typedef __attribute__((ext_vector_type(8))) short short8;
typedef __attribute__((ext_vector_type(4))) float f32x4;
typedef __attribute__((ext_vector_type(4))) ushort us4;

constexpr int BS = 2, C_IN = 8, CTX = 1024, TGT = 96;
constexpr int DM = 256, NH = 16, DFF = 1024, NL = 4;
constexpr int NF = 256, TOTAL = 320;
constexpr int NB = 16;
constexpr int DK = 16;
constexpr float EPS = 1e-5f;
constexpr float SCALE = 0.25f;
constexpr int KHEAD = DM * TOTAL;  // 81920
constexpr int M = NB * TOTAL;      // 5120

__device__ __forceinline__ ushort f2b(float x) {
    uint u = __float_as_uint(x);
    u += 0x7fff + ((u >> 16) & 1);
    return (ushort)(u >> 16);
}
__device__ __forceinline__ float bu2f(ushort x) { return __uint_as_float(((uint)x) << 16); }
__device__ __forceinline__ uint pack2(float a, float b) { return (uint)f2b(a) | ((uint)f2b(b) << 16); }

typedef __attribute__((address_space(3))) uint lds_u32;
typedef const __attribute__((address_space(1))) uint glb_u32;
__device__ __forceinline__ void ldst16(const void* g, void* l) {
    __builtin_amdgcn_global_load_lds((glb_u32*)g, (lds_u32*)l, 16, 0, 0);
}

#define PIPE_BARRIER() asm volatile("s_waitcnt vmcnt(0)\n\ts_barrier" ::: "memory")

// ---------------- prep v2: vectorized weight transposes + RevIN + embed + out-init ----------------
__global__ __launch_bounds__(256) void k_prep(
        const float* __restrict__ WQ, const float* __restrict__ WK,
        const float* __restrict__ WV, const float* __restrict__ WO,
        const float* __restrict__ F1, const float* __restrict__ F2,
        const float* __restrict__ Wh,
        ushort* __restrict__ Wtqkv, ushort* __restrict__ WtO,
        ushort* __restrict__ Ft1, ushort* __restrict__ Ft2,
        ushort* __restrict__ WhT2,
        const float* __restrict__ z, const float* __restrict__ rw,
        const float* __restrict__ rb,
        const float* __restrict__ Wf, const float* __restrict__ bfv,
        const float* __restrict__ Wc, const float* __restrict__ bcv,
        const float* __restrict__ Wpos, ushort* __restrict__ u,
        const float* __restrict__ bhv, float* __restrict__ outp,
        float* __restrict__ scalef) {
    __shared__ __align__(16) ushort tile[64 * 98];
    __shared__ float szn[CTX];
    __shared__ float red1[4], red2[4];
    int i = blockIdx.x, tid = threadIdx.x;

    if (i < 768) {
        const float* src; ushort* dst; int lsrc, ldst_, r0, c0;
        if (i < 256) {
            int mat = i >> 4, l = mat >> 2, w = mat & 3;
            src = (w == 0 ? WQ : (w == 1 ? WK : (w == 2 ? WV : WO))) + l * 65536;
            dst = (w < 3) ? (Wtqkv + (size_t)l * 768 * 256 + w * 65536)
                          : (WtO + (size_t)l * 65536);
            lsrc = 256; ldst_ = 256; r0 = ((i >> 2) & 3) * 64; c0 = (i & 3) * 64;
        } else if (i < 512) {
            int j = i - 256, l = j >> 6, t = j & 63;
            src = F1 + (size_t)l * 262144; dst = Ft1 + (size_t)l * 262144;
            lsrc = 1024; ldst_ = 256; r0 = (t >> 4) * 64; c0 = (t & 15) * 64;
        } else {
            int j = i - 512, l = j >> 6, t = j & 63;
            src = F2 + (size_t)l * 262144; dst = Ft2 + (size_t)l * 262144;
            lsrc = 256; ldst_ = 1024; r0 = (t >> 2) * 64; c0 = (t & 3) * 64;
        }
#pragma unroll
        for (int it = 0; it < 4; it++) {
            int fid = it * 256 + tid;
            int fr = fid >> 4, fc = fid & 15;
            f32x4 v = *(const f32x4*)&src[(size_t)(r0 + fr) * lsrc + c0 + fc * 4];
            ushort* tr = &tile[fr * 66];
            tr[fc * 4 + 0] = f2b(v[0]); tr[fc * 4 + 1] = f2b(v[1]);
            tr[fc * 4 + 2] = f2b(v[2]); tr[fc * 4 + 3] = f2b(v[3]);
        }
        __syncthreads();
#pragma unroll
        for (int it = 0; it < 4; it++) {
            int sid = it * 256 + tid;
            int cr = sid >> 4, cc = sid & 15;
            us4 v = (us4){ tile[(cc * 4 + 0) * 66 + cr], tile[(cc * 4 + 1) * 66 + cr],
                           tile[(cc * 4 + 2) * 66 + cr], tile[(cc * 4 + 3) * 66 + cr] };
            *(us4*)&dst[(size_t)(c0 + cr) * ldst_ + r0 + cc * 4] = v;
        }
    } else if (i < 2048) {
        int j = i - 768;
        int pp = j >> 2, d0 = (j & 3) * 64;
#pragma unroll
        for (int it = 0; it < 6; it++) {
            int fid = it * 256 + tid;
            int fr = fid / 24, fc = fid % 24;
            f32x4 v = *(const f32x4*)&Wh[((size_t)(d0 + fr) * 320 + pp) * 96 + fc * 4];
            ushort* tr = &tile[fr * 98];
            tr[fc * 4 + 0] = f2b(v[0]); tr[fc * 4 + 1] = f2b(v[1]);
            tr[fc * 4 + 2] = f2b(v[2]); tr[fc * 4 + 3] = f2b(v[3]);
        }
        __syncthreads();
#pragma unroll
        for (int it = 0; it < 6; it++) {
            int sid = it * 256 + tid;
            int tr = sid >> 4, dc = sid & 15;
            us4 v = (us4){ tile[(dc * 4 + 0) * 98 + tr], tile[(dc * 4 + 1) * 98 + tr],
                           tile[(dc * 4 + 2) * 98 + tr], tile[(dc * 4 + 3) * 98 + tr] };
            *(us4*)&WhT2[(size_t)tr * KHEAD + pp * 256 + d0 + dc * 4] = v;
        }
    } else {
        int j = i - 2048;
        int bc = j / 80, pb = j % 80;
        int wave = tid >> 6, lane = tid & 63;
        f32x4 zv = *(const f32x4*)&z[bc * CTX + tid * 4];
        float s1 = zv[0] + zv[1] + zv[2] + zv[3];
        float s2 = zv[0] * zv[0] + zv[1] * zv[1] + zv[2] * zv[2] + zv[3] * zv[3];
#pragma unroll
        for (int off = 1; off < 64; off <<= 1) {
            s1 += __shfl_xor(s1, off);
            s2 += __shfl_xor(s2, off);
        }
        if (lane == 0) { red1[wave] = s1; red2[wave] = s2; }
        __syncthreads();
        s1 = red1[0] + red1[1] + red1[2] + red1[3];
        s2 = red2[0] + red2[1] + red2[2] + red2[3];
        float m = s1 * (1.0f / CTX);
        float var = s2 * (1.0f / CTX) - m * m;
        float sd = sqrtf(var + EPS);
        int c = bc & 7;
        float w = rw[c], bb = rb[c];
        float inv_sd_w = w / sd;
#pragma unroll
        for (int k = 0; k < 4; k++) szn[tid * 4 + k] = (zv[k] - m) * inv_sd_w + bb;
        if (pb == 0) {
            if (tid < TGT) outp[bc * TGT + tid] = (bhv[tid] - bb) / (w + EPS * EPS) * sd + m;
            if (tid == 0) scalef[bc] = sd / (w + EPS * EPS);
        }
        __syncthreads();
#pragma unroll
        for (int pi = 0; pi < 4; pi++) {
            int p = pb * 4 + pi, d = tid;
            float acc;
            if (p < NF) {
                acc = bfv[d];
                int base = p * 4;
#pragma unroll
                for (int q = 0; q < 8; q++)
                    acc += szn[min(base + q, CTX - 1)] * Wf[q * DM + d];
            } else {
                acc = bcv[d];
                int base = (p - NF) * 16;
#pragma unroll
                for (int q = 0; q < 32; q++)
                    acc += szn[min(base + q, CTX - 1)] * Wc[q * DM + d];
            }
            acc += Wpos[p * DM + d];
            u[((size_t)bc * TOTAL + p) * DM + d] = f2b(acc);
        }
    }
}

// ---------------- bf16 MFMA GEMM, 64x64 tile, 2-phase double-buffered (stable r5 form) ----------------
template <int GELU, int QKV>
__global__ __launch_bounds__(256) void k_gemm_mfma(const ushort* __restrict__ A,
                                                   const ushort* __restrict__ Wt,
                                                   const float* __restrict__ b0,
                                                   const float* __restrict__ b1,
                                                   const float* __restrict__ b2,
                                                   ushort* __restrict__ C,
                                                   ushort* __restrict__ C2,
                                                   int Mm, int N, int K) {
    __shared__ ushort As[2][64][32];
    __shared__ ushort Bs[2][64][32];
    int tid = threadIdx.x;
    int wave = tid >> 6, lane = tid & 63;
    int quad = lane >> 4, l16 = lane & 15;
    int m0 = blockIdx.y * 64, n0 = blockIdx.x * 64;

    f32x4 acc[4];
#pragma unroll
    for (int nt = 0; nt < 4; nt++) acc[nt] = (f32x4){0.f, 0.f, 0.f, 0.f};

    int srow = wave * 16 + (lane >> 2);
    int sc = (lane & 3) ^ ((srow >> 1) & 3);
    const ushort* Ag = &A[(size_t)(m0 + srow) * K + sc * 8];
    const ushort* Bg = &Wt[(size_t)(n0 + srow) * K + sc * 8];
    int rchunk = (quad ^ ((l16 >> 1) & 3)) * 8;

    ldst16(Ag, &As[0][wave * 16][0]);
    ldst16(Bg, &Bs[0][wave * 16][0]);
    PIPE_BARRIER();

    int nstep = K >> 5;
    int cur = 0;
    for (int t = 0; t < nstep; t++) {
        if (t + 1 < nstep) {
            ldst16(Ag + (t + 1) * 32, &As[cur ^ 1][wave * 16][0]);
            ldst16(Bg + (t + 1) * 32, &Bs[cur ^ 1][wave * 16][0]);
        }
        short8 af = *(const short8*)&As[cur][wave * 16 + l16][rchunk];
#pragma unroll
        for (int nt = 0; nt < 4; nt++) {
            short8 bf = *(const short8*)&Bs[cur][nt * 16 + l16][rchunk];
            acc[nt] = __builtin_amdgcn_mfma_f32_16x16x32_bf16(af, bf, acc[nt], 0, 0, 0);
        }
        PIPE_BARRIER();
        cur ^= 1;
    }
#pragma unroll
    for (int nt = 0; nt < 4; nt++) {
        int col = n0 + nt * 16 + l16;
        float bi;
        if (QKV) {
            int bs = (n0 + nt * 16) >> 8;
            const float* bp = bs == 0 ? b0 : (bs == 1 ? b1 : b2);
            bi = bp[col & 255];
        } else {
            bi = b0[col];
        }
#pragma unroll
        for (int r = 0; r < 4; r++) {
            int rowm = m0 + wave * 16 + quad * 4 + r;
            float vv = acc[nt][r] + bi;
            if (GELU) vv = vv * 0.5f * (1.0f + erff(vv * 0.70710678118f));
            if (QKV) {
                int bs = col >> 8;
                ushort* dst = (bs == 2) ? (C2 + (size_t)rowm * DM)
                                        : (C + (size_t)bs * (M * DM) + (size_t)rowm * DM);
                dst[col & 255] = f2b(vv);
            } else {
                C[(size_t)rowm * N + col] = f2b(vv);
            }
        }
    }
}

// ---------------- GEMM(16x256) + bias + residual + LayerNorm (O-proj), stable r5 form ----------------
__global__ __launch_bounds__(256) void k_gemm_ln16(const ushort* __restrict__ A,
                                                   const ushort* __restrict__ Wt,
                                                   const float* __restrict__ bias,
                                                   const float* __restrict__ ls,
                                                   const float* __restrict__ lb,
                                                   ushort* __restrict__ u, int K) {
    __shared__ ushort As[2][16][32];
    __shared__ ushort Bs[2][256][32];
    __shared__ float ps1[16][4], ps2[16][4];
    int tid = threadIdx.x;
    int wave = tid >> 6, lane = tid & 63;
    int quad = lane >> 4, l16 = lane & 15;
    int m0 = blockIdx.x * 16;

    f32x4 acc[4];
#pragma unroll
    for (int nt = 0; nt < 4; nt++) acc[nt] = (f32x4){0.f, 0.f, 0.f, 0.f};

    int brow = wave * 16 + (lane >> 2);
    int bc_swz = (lane & 3) ^ ((brow >> 1) & 3);
    const ushort* Bg0 = &Wt[(size_t)brow * K + bc_swz * 8];
    int ar = lane >> 2;
    int ac = (lane & 3) ^ ((ar >> 1) & 3);
    const ushort* Ag = &A[(size_t)(m0 + ar) * K + ac * 8];
    int rchunk = (quad ^ ((l16 >> 1) & 3)) * 8;

    if (tid < 64) ldst16(Ag, &As[0][0][0]);
#pragma unroll
    for (int i = 0; i < 4; i++)
        ldst16(Bg0 + (size_t)i * 64 * K, &Bs[0][i * 64 + wave * 16][0]);
    PIPE_BARRIER();

    int nstep = K >> 5;
    int cur = 0;
    for (int t = 0; t < nstep; t++) {
        if (t + 1 < nstep) {
            if (tid < 64) ldst16(Ag + (t + 1) * 32, &As[cur ^ 1][0][0]);
#pragma unroll
            for (int i = 0; i < 4; i++)
                ldst16(Bg0 + (size_t)i * 64 * K + (t + 1) * 32, &Bs[cur ^ 1][i * 64 + wave * 16][0]);
        }
        short8 af = *(const short8*)&As[cur][l16][rchunk];
#pragma unroll
        for (int nt = 0; nt < 4; nt++) {
            short8 bf = *(const short8*)&Bs[cur][wave * 64 + nt * 16 + l16][rchunk];
            acc[nt] = __builtin_amdgcn_mfma_f32_16x16x32_bf16(af, bf, acc[nt], 0, 0, 0);
        }
        PIPE_BARRIER();
        cur ^= 1;
    }
    float xv[4][4];
#pragma unroll
    for (int r = 0; r < 4; r++) {
        int rowg = m0 + quad * 4 + r;
        float s1 = 0.f, s2 = 0.f;
#pragma unroll
        for (int nt = 0; nt < 4; nt++) {
            int col = wave * 64 + nt * 16 + l16;
            float x = acc[nt][r] + bias[col] + bu2f(u[(size_t)rowg * DM + col]);
            xv[r][nt] = x; s1 += x; s2 += x * x;
        }
        s1 += __shfl_xor(s1, 1); s2 += __shfl_xor(s2, 1);
        s1 += __shfl_xor(s1, 2); s2 += __shfl_xor(s2, 2);
        s1 += __shfl_xor(s1, 4); s2 += __shfl_xor(s2, 4);
        s1 += __shfl_xor(s1, 8); s2 += __shfl_xor(s2, 8);
        if (l16 == 0) { ps1[quad * 4 + r][wave] = s1; ps2[quad * 4 + r][wave] = s2; }
    }
    __syncthreads();
#pragma unroll
    for (int r = 0; r < 4; r++) {
        int rowl = quad * 4 + r, rowg = m0 + rowl;
        float s1 = ps1[rowl][0] + ps1[rowl][1] + ps1[rowl][2] + ps1[rowl][3];
        float s2 = ps2[rowl][0] + ps2[rowl][1] + ps2[rowl][2] + ps2[rowl][3];
        float m = s1 * (1.0f / DM);
        float var = s2 * (1.0f / DM) - m * m;
        float rs = rsqrtf(var + EPS);
#pragma unroll
        for (int nt = 0; nt < 4; nt++) {
            int col = wave * 64 + nt * 16 + l16;
            u[(size_t)rowg * DM + col] = f2b((xv[r][nt] - m) * rs * ls[col] + lb[col]);
        }
    }
}

// ---------------- fused FFN: gelu(u@F1+c1)@F2+c2 + residual + LN2, h in LDS ----------------
// block = 16 rows. Phase A: wave w computes h[:, w*256..w*256+256) (128 MFMA), gelu, -> LDS.
// Phase B: wave w computes y[:, w*64..w*64+64) with K=1024 over LDS h (128 MFMA), then LN.
__global__ __launch_bounds__(256) void k_ffn(const ushort* __restrict__ u_in,
                                             const ushort* __restrict__ F1t,  // [1024][256]
                                             const ushort* __restrict__ F2t,  // [256][1024]
                                             const float* __restrict__ c1v,
                                             const float* __restrict__ c2v,
                                             const float* __restrict__ ls,
                                             const float* __restrict__ lb,
                                             ushort* __restrict__ u) {
    __shared__ __align__(16) ushort Au[16][264];    // u rows, swizzled, +pad
    __shared__ __align__(16) ushort Hs[16][1032];   // h rows, swizzled, +pad
    __shared__ float ps1[16][4], ps2[16][4];
    int tid = threadIdx.x;
    int wave = tid >> 6, lane = tid & 63;
    int quad = lane >> 4, l16 = lane & 15;
    int m0 = blockIdx.x * 16;

    // stage u rows (XOR swizzle per 32-col k-step: phys chunk p holds logical p^((row>>1)&3))
    for (int s = tid; s < 512; s += 256) {
        int row = s >> 5, k32 = (s >> 2) & 7, pp = s & 3;
        int logical = pp ^ ((row >> 1) & 3);
        short8 v = *(const short8*)&u_in[(size_t)(m0 + row) * DM + k32 * 32 + logical * 8];
        *(short8*)&Au[row][k32 * 32 + pp * 8] = v;
    }
    __syncthreads();

    int rchunk = (quad ^ ((l16 >> 1) & 3)) * 8;

    // ---- phase A: h slice for this wave ----
    for (int ct = 0; ct < 16; ct++) {
        f32x4 acc = (f32x4){0.f, 0.f, 0.f, 0.f};
        int coln = wave * 256 + ct * 16 + l16;
        const ushort* brow = &F1t[(size_t)coln * DM + quad * 8];
#pragma unroll
        for (int t = 0; t < 8; t++) {
            short8 af = *(const short8*)&Au[l16][t * 32 + rchunk];
            short8 bf = *(const short8*)&brow[t * 32];
            acc = __builtin_amdgcn_mfma_f32_16x16x32_bf16(af, bf, acc, 0, 0, 0);
        }
        int k32 = coln >> 5, p = (coln >> 3) & 3, e = coln & 7;
        float bi = c1v[coln];
#pragma unroll
        for (int r = 0; r < 4; r++) {
            int row = quad * 4 + r;
            float vv = acc[r] + bi;
            vv = vv * 0.5f * (1.0f + erff(vv * 0.70710678118f));
            int pphys = p ^ ((row >> 1) & 3);
            Hs[row][k32 * 32 + pphys * 8 + e] = f2b(vv);
        }
    }
    __syncthreads();

    // ---- phase B: y slice (64 cols) over K=1024 from LDS h ----
    f32x4 acc[4];
#pragma unroll
    for (int nt = 0; nt < 4; nt++) acc[nt] = (f32x4){0.f, 0.f, 0.f, 0.f};
#pragma unroll 2
    for (int t = 0; t < 32; t++) {
        short8 af = *(const short8*)&Hs[l16][t * 32 + rchunk];
#pragma unroll
        for (int nt = 0; nt < 4; nt++) {
            int coln = wave * 64 + nt * 16 + l16;
            short8 bf = *(const short8*)&F2t[(size_t)coln * DFF + t * 32 + quad * 8];
            acc[nt] = __builtin_amdgcn_mfma_f32_16x16x32_bf16(af, bf, acc[nt], 0, 0, 0);
        }
    }

    // ---- epilogue: bias + residual (from Au) + LayerNorm ----
    float xv[4][4];
#pragma unroll
    for (int r = 0; r < 4; r++) {
        int row = quad * 4 + r;
        float s1 = 0.f, s2 = 0.f;
#pragma unroll
        for (int nt = 0; nt < 4; nt++) {
            int col = wave * 64 + nt * 16 + l16;
            int k32 = col >> 5, p = (col >> 3) & 3, e = col & 7;
            int pphys = p ^ ((row >> 1) & 3);
            float x = acc[nt][r] + c2v[col] + bu2f(Au[row][k32 * 32 + pphys * 8 + e]);
            xv[r][nt] = x; s1 += x; s2 += x * x;
        }
        s1 += __shfl_xor(s1, 1); s2 += __shfl_xor(s2, 1);
        s1 += __shfl_xor(s1, 2); s2 += __shfl_xor(s2, 2);
        s1 += __shfl_xor(s1, 4); s2 += __shfl_xor(s2, 4);
        s1 += __shfl_xor(s1, 8); s2 += __shfl_xor(s2, 8);
        if (l16 == 0) { ps1[quad * 4 + r][wave] = s1; ps2[quad * 4 + r][wave] = s2; }
    }
    __syncthreads();
#pragma unroll
    for (int r = 0; r < 4; r++) {
        int rowl = quad * 4 + r, rowg = m0 + rowl;
        float s1 = ps1[rowl][0] + ps1[rowl][1] + ps1[rowl][2] + ps1[rowl][3];
        float s2 = ps2[rowl][0] + ps2[rowl][1] + ps2[rowl][2] + ps2[rowl][3];
        float m = s1 * (1.0f / DM);
        float var = s2 * (1.0f / DM) - m * m;
        float rs = rsqrtf(var + EPS);
#pragma unroll
        for (int nt = 0; nt < 4; nt++) {
            int col = wave * 64 + nt * 16 + l16;
            u[(size_t)rowg * DM + col] = f2b((xv[r][nt] - m) * rs * ls[col] + lb[col]);
        }
    }
}

// ---------------- MFMA fused attention: residual scores recomputed; K double-buffered ----------------
__global__ __launch_bounds__(256, 4) void k_attn(const ushort* __restrict__ qk, const ushort* __restrict__ vm,
                                                 ushort* __restrict__ ao, int nj) {
    __shared__ ushort sh[15360];
    uint* sh32 = (uint*)sh;
    int bh = blockIdx.x, b = bh >> 4, h = bh & 15;
    int i0 = blockIdx.y * 64;
    int t = threadIdx.x, wave = t >> 6, lane = t & 63, quad = lane >> 4, l16 = lane & 15;
    const short8 zero8 = (short8){0, 0, 0, 0, 0, 0, 0, 0};

    f32x4 acc[20];
#pragma unroll
    for (int nt = 0; nt < 20; nt++) acc[nt] = (f32x4){0.f, 0.f, 0.f, 0.f};

    for (int idx = t; idx < 320; idx += 256) {
        int jp = idx >> 1, dh = idx & 1;
        int j = jp * 2;
        uint4 a = *(const uint4*)&vm[((size_t)b * TOTAL + j) * DM + h * DK + dh * 8];
        uint4 bb = *(const uint4*)&vm[((size_t)b * TOTAL + j + 1) * DM + h * DK + dh * 8];
        const ushort* ap = (const ushort*)&a;
        const ushort* bp = (const ushort*)&bb;
        int jr = j & 31;
        int q = (jr & 15) >> 2, jj = ((jr >> 4) << 2) + (jr & 3);
        int base = 10240 + ((j >> 5) * 4 + q) * 128 + jj;
#pragma unroll
        for (int dd = 0; dd < 8; dd++) {
            int d = dh * 8 + dd;
            uint val = (uint)ap[dd] | ((uint)bp[dd] << 16);
            sh32[(base + d * 8) >> 1] = val;
        }
    }

    for (int jl = 0; jl < nj; jl++) {
        const ushort* qm = qk + (size_t)(2 * jl) * M * DM;
        const ushort* km = qm + (size_t)M * DM;
        int kb = (jl & 1) * 5120;
        for (int idx = t; idx < 640; idx += 256) {
            int j = idx >> 1, half = idx & 1;
            short8 kv = *(const short8*)&km[((size_t)b * TOTAL + j) * DM + h * DK + half * 8];
            int jt = j >> 4, jln = j & 15;
            *(short8*)&sh[kb + ((jt * 2 + half) * 16 + jln) * 8] = kv;
        }
        short8 qf = zero8;
        if (quad < 2) qf = *(const short8*)&qm[((size_t)b * TOTAL + i0 + wave * 16 + l16) * DM + h * DK + quad * 8];
        __syncthreads();
#pragma unroll
        for (int nt = 0; nt < 20; nt++) {
            short8 kf = *(const short8*)&sh[kb + ((nt * 2 + (quad & 1)) * 16 + l16) * 8];
            acc[nt] = __builtin_amdgcn_mfma_f32_16x16x32_bf16(kf, qf, acc[nt], 0, 0, 0);
        }
    }

    float mx = -1e30f;
#pragma unroll
    for (int nt = 0; nt < 20; nt++)
#pragma unroll
        for (int r = 0; r < 4; r++) { acc[nt][r] *= SCALE; mx = fmaxf(mx, acc[nt][r]); }
    mx = fmaxf(mx, __shfl_xor(mx, 16));
    mx = fmaxf(mx, __shfl_xor(mx, 32));
    float sum = 0.f;
#pragma unroll
    for (int nt = 0; nt < 20; nt++)
#pragma unroll
        for (int r = 0; r < 4; r++) { acc[nt][r] = __expf(acc[nt][r] - mx); sum += acc[nt][r]; }
    sum += __shfl_xor(sum, 16);
    sum += __shfl_xor(sum, 32);
    float inv = 1.f / sum;
#pragma unroll
    for (int nt = 0; nt < 20; nt++)
#pragma unroll
        for (int r = 0; r < 4; r++) acc[nt][r] *= inv;

    f32x4 oacc = (f32x4){0.f, 0.f, 0.f, 0.f};
#pragma unroll
    for (int jt2 = 0; jt2 < 10; jt2++) {
        short8 vt = *(const short8*)&sh[10240 + ((jt2 * 4 + quad) * 16 + l16) * 8];
        union { short8 v; uint u[4]; } pf;
        pf.u[0] = pack2(acc[2 * jt2][0], acc[2 * jt2][1]);
        pf.u[1] = pack2(acc[2 * jt2][2], acc[2 * jt2][3]);
        pf.u[2] = pack2(acc[2 * jt2 + 1][0], acc[2 * jt2 + 1][1]);
        pf.u[3] = pack2(acc[2 * jt2 + 1][2], acc[2 * jt2 + 1][3]);
        oacc = __builtin_amdgcn_mfma_f32_16x16x32_bf16(vt, pf.v, oacc, 0, 0, 0);
    }
    us4 ov4 = (us4){f2b(oacc[0]), f2b(oacc[1]), f2b(oacc[2]), f2b(oacc[3])};
    *(us4*)&ao[((size_t)b * TOTAL + i0 + wave * 16 + l16) * DM + h * DK + quad * 4] = ov4;
}

// ---------------- head GEMM: MFMA split-K, atomic accumulate into pre-initialized out ----------------
__global__ __launch_bounds__(256) void k_head(const ushort* __restrict__ u, const ushort* __restrict__ WhT2,
                                              const float* __restrict__ scalef, float* __restrict__ out) {
    int t0 = blockIdx.x * 16;
    int wave = threadIdx.x >> 6, lane = threadIdx.x & 63;
    int quad = lane >> 4, l16 = lane & 15;
    int chunk = blockIdx.y * 4 + wave;
    int kbeg = chunk * 1024;
    f32x4 acc = (f32x4){0.f, 0.f, 0.f, 0.f};
    const ushort* za = &u[(size_t)l16 * KHEAD + quad * 8];
    const ushort* wb = &WhT2[(size_t)(t0 + l16) * KHEAD + quad * 8];
#pragma unroll 4
    for (int k = kbeg; k < kbeg + 1024; k += 32) {
        short8 af = *(const short8*)&za[k];
        short8 bf = *(const short8*)&wb[k];
        acc = __builtin_amdgcn_mfma_f32_16x16x32_bf16(af, bf, acc, 0, 0, 0);
    }
#pragma unroll
    for (int r = 0; r < 4; r++) {
        int bcr = quad * 4 + r;
        atomicAdd(&out[bcr * TGT + t0 + l16], acc[r] * scalef[bcr]);
    }
}

extern "C" void kernel_launch(void* const* d_in, const int* in_sizes, int n_in,
                              void* d_out, int out_size, void* d_ws, size_t ws_size,
                              hipStream_t stream) {
    const float* z       = (const float*)d_in[0];
    const float* revin_w = (const float*)d_in[1];
    const float* revin_b = (const float*)d_in[2];
    const float* Wf      = (const float*)d_in[3];
    const float* bfv     = (const float*)d_in[4];
    const float* Wc      = (const float*)d_in[5];
    const float* bcv     = (const float*)d_in[6];
    const float* Wpos    = (const float*)d_in[7];
    const float* WQ      = (const float*)d_in[8];
    const float* bQ      = (const float*)d_in[9];
    const float* WK      = (const float*)d_in[10];
    const float* bK      = (const float*)d_in[11];
    const float* WV      = (const float*)d_in[12];
    const float* bV      = (const float*)d_in[13];
    const float* WO      = (const float*)d_in[14];
    const float* bO      = (const float*)d_in[15];
    const float* ln1s    = (const float*)d_in[16];
    const float* ln1b    = (const float*)d_in[17];
    const float* ln2s    = (const float*)d_in[18];
    const float* ln2b    = (const float*)d_in[19];
    const float* F1      = (const float*)d_in[20];
    const float* c1      = (const float*)d_in[21];
    const float* F2      = (const float*)d_in[22];
    const float* c2      = (const float*)d_in[23];
    const float* Wh      = (const float*)d_in[24];
    const float* bh      = (const float*)d_in[25];
    float* out = (float*)d_out;

    char* p = (char*)d_ws;
    float* scalef = (float*)p;   p += 16 * 4;
    p = (char*)(((size_t)p + 255) & ~255ull);
    ushort* u     = (ushort*)p;  p += (size_t)M * DM * 2;
    ushort* qkbuf = (ushort*)p;  p += (size_t)NL * 2 * M * DM * 2;   // per-layer [Q_l, K_l]
    ushort* vbuf  = (ushort*)p;  p += (size_t)M * DM * 2;
    ushort* ax    = (ushort*)p;  p += (size_t)M * DM * 2;
    ushort* Wtqkv = (ushort*)p;  p += (size_t)NL * 768 * 256 * 2;
    ushort* WtO   = (ushort*)p;  p += (size_t)NL * 256 * 256 * 2;
    ushort* Ft1   = (ushort*)p;  p += (size_t)NL * 1024 * 256 * 2;
    ushort* Ft2   = (ushort*)p;  p += (size_t)NL * 256 * 1024 * 2;
    ushort* WhT2  = (ushort*)p;  p += (size_t)TGT * KHEAD * 2;

    k_prep<<<3328, 256, 0, stream>>>(WQ, WK, WV, WO, F1, F2, Wh,
                                     Wtqkv, WtO, Ft1, Ft2, WhT2,
                                     z, revin_w, revin_b,
                                     Wf, bfv, Wc, bcv, Wpos, u,
                                     bh, out, scalef);

    for (int l = 0; l < NL; l++) {
        k_gemm_mfma<0, 1><<<dim3(12, 80), 256, 0, stream>>>(
            u, Wtqkv + (size_t)l * 768 * 256, bQ + l * DM, bK + l * DM, bV + l * DM,
            qkbuf + (size_t)l * 2 * M * DM, vbuf, M, 768, 256);
        k_attn<<<dim3(NB * NH, 5), 256, 0, stream>>>(qkbuf, vbuf, ax, l + 1);
        k_gemm_ln16<<<M / 16, 256, 0, stream>>>(
            ax, WtO + (size_t)l * 65536, bO + l * DM, ln1s + l * DM, ln1b + l * DM, u, 256);
        k_ffn<<<M / 16, 256, 0, stream>>>(
            u, Ft1 + (size_t)l * 262144, Ft2 + (size_t)l * 262144,
            c1 + l * DFF, c2 + l * DM, ln2s + l * DM, ln2b + l * DM, u);
    }

    k_head<<<dim3(TGT / 16, 20), 256, 0, stream>>>(u, WhT2, scalef, out);
}

// Round 9
// 427.723 us; speedup vs baseline: 1.2689x; 1.2689x over previous
//
#include <hip/hip_runtime.h>
#include <math.h>

typedef unsigned short ushort;
typedef unsigned int uint;
typedef __attribute__((ext_vector_type(8))) short short8;
typedef __attribute__((ext_vector_type(4))) float f32x4;
typedef __attribute__((ext_vector_type(4))) ushort us4;

constexpr int BS = 2, C_IN = 8, CTX = 1024, TGT = 96;
constexpr int DM = 256, NH = 16, DFF = 1024, NL = 4;
constexpr int NF = 256, TOTAL = 320;
constexpr int NB = 16;
constexpr int DK = 16;
constexpr float EPS = 1e-5f;
constexpr float SCALE = 0.25f;
constexpr int KHEAD = DM * TOTAL;  // 81920
constexpr int M = NB * TOTAL;      // 5120

__device__ __forceinline__ ushort f2b(float x) {
    uint u = __float_as_uint(x);
    u += 0x7fff + ((u >> 16) & 1);
    return (ushort)(u >> 16);
}
__device__ __forceinline__ float bu2f(ushort x) { return __uint_as_float(((uint)x) << 16); }
__device__ __forceinline__ uint pack2(float a, float b) { return (uint)f2b(a) | ((uint)f2b(b) << 16); }

typedef __attribute__((address_space(3))) uint lds_u32;
typedef const __attribute__((address_space(1))) uint glb_u32;
__device__ __forceinline__ void ldst16(const void* g, void* l) {
    __builtin_amdgcn_global_load_lds((glb_u32*)g, (lds_u32*)l, 16, 0, 0);
}

#define PIPE_BARRIER() asm volatile("s_waitcnt vmcnt(0)\n\ts_barrier" ::: "memory")

// ---------------- prep v2: vectorized weight transposes + RevIN + embed + out-init ----------------
__global__ __launch_bounds__(256) void k_prep(
        const float* __restrict__ WQ, const float* __restrict__ WK,
        const float* __restrict__ WV, const float* __restrict__ WO,
        const float* __restrict__ F1, const float* __restrict__ F2,
        const float* __restrict__ Wh,
        ushort* __restrict__ Wtqkv, ushort* __restrict__ WtO,
        ushort* __restrict__ Ft1, ushort* __restrict__ Ft2,
        ushort* __restrict__ WhT2,
        const float* __restrict__ z, const float* __restrict__ rw,
        const float* __restrict__ rb,
        const float* __restrict__ Wf, const float* __restrict__ bfv,
        const float* __restrict__ Wc, const float* __restrict__ bcv,
        const float* __restrict__ Wpos, ushort* __restrict__ u,
        const float* __restrict__ bhv, float* __restrict__ outp,
        float* __restrict__ scalef) {
    __shared__ __align__(16) ushort tile[64 * 98];
    __shared__ float szn[CTX];
    __shared__ float red1[4], red2[4];
    int i = blockIdx.x, tid = threadIdx.x;

    if (i < 768) {
        const float* src; ushort* dst; int lsrc, ldst_, r0, c0;
        if (i < 256) {
            int mat = i >> 4, l = mat >> 2, w = mat & 3;
            src = (w == 0 ? WQ : (w == 1 ? WK : (w == 2 ? WV : WO))) + l * 65536;
            dst = (w < 3) ? (Wtqkv + (size_t)l * 768 * 256 + w * 65536)
                          : (WtO + (size_t)l * 65536);
            lsrc = 256; ldst_ = 256; r0 = ((i >> 2) & 3) * 64; c0 = (i & 3) * 64;
        } else if (i < 512) {
            int j = i - 256, l = j >> 6, t = j & 63;
            src = F1 + (size_t)l * 262144; dst = Ft1 + (size_t)l * 262144;
            lsrc = 1024; ldst_ = 256; r0 = (t >> 4) * 64; c0 = (t & 15) * 64;
        } else {
            int j = i - 512, l = j >> 6, t = j & 63;
            src = F2 + (size_t)l * 262144; dst = Ft2 + (size_t)l * 262144;
            lsrc = 256; ldst_ = 1024; r0 = (t >> 2) * 64; c0 = (t & 3) * 64;
        }
#pragma unroll
        for (int it = 0; it < 4; it++) {
            int fid = it * 256 + tid;
            int fr = fid >> 4, fc = fid & 15;
            f32x4 v = *(const f32x4*)&src[(size_t)(r0 + fr) * lsrc + c0 + fc * 4];
            ushort* tr = &tile[fr * 66];
            tr[fc * 4 + 0] = f2b(v[0]); tr[fc * 4 + 1] = f2b(v[1]);
            tr[fc * 4 + 2] = f2b(v[2]); tr[fc * 4 + 3] = f2b(v[3]);
        }
        __syncthreads();
#pragma unroll
        for (int it = 0; it < 4; it++) {
            int sid = it * 256 + tid;
            int cr = sid >> 4, cc = sid & 15;
            us4 v = (us4){ tile[(cc * 4 + 0) * 66 + cr], tile[(cc * 4 + 1) * 66 + cr],
                           tile[(cc * 4 + 2) * 66 + cr], tile[(cc * 4 + 3) * 66 + cr] };
            *(us4*)&dst[(size_t)(c0 + cr) * ldst_ + r0 + cc * 4] = v;
        }
    } else if (i < 2048) {
        int j = i - 768;
        int pp = j >> 2, d0 = (j & 3) * 64;
#pragma unroll
        for (int it = 0; it < 6; it++) {
            int fid = it * 256 + tid;
            int fr = fid / 24, fc = fid % 24;
            f32x4 v = *(const f32x4*)&Wh[((size_t)(d0 + fr) * 320 + pp) * 96 + fc * 4];
            ushort* tr = &tile[fr * 98];
            tr[fc * 4 + 0] = f2b(v[0]); tr[fc * 4 + 1] = f2b(v[1]);
            tr[fc * 4 + 2] = f2b(v[2]); tr[fc * 4 + 3] = f2b(v[3]);
        }
        __syncthreads();
#pragma unroll
        for (int it = 0; it < 6; it++) {
            int sid = it * 256 + tid;
            int tr = sid >> 4, dc = sid & 15;
            us4 v = (us4){ tile[(dc * 4 + 0) * 98 + tr], tile[(dc * 4 + 1) * 98 + tr],
                           tile[(dc * 4 + 2) * 98 + tr], tile[(dc * 4 + 3) * 98 + tr] };
            *(us4*)&WhT2[(size_t)tr * KHEAD + pp * 256 + d0 + dc * 4] = v;
        }
    } else {
        int j = i - 2048;
        int bc = j / 80, pb = j % 80;
        int wave = tid >> 6, lane = tid & 63;
        f32x4 zv = *(const f32x4*)&z[bc * CTX + tid * 4];
        float s1 = zv[0] + zv[1] + zv[2] + zv[3];
        float s2 = zv[0] * zv[0] + zv[1] * zv[1] + zv[2] * zv[2] + zv[3] * zv[3];
#pragma unroll
        for (int off = 1; off < 64; off <<= 1) {
            s1 += __shfl_xor(s1, off);
            s2 += __shfl_xor(s2, off);
        }
        if (lane == 0) { red1[wave] = s1; red2[wave] = s2; }
        __syncthreads();
        s1 = red1[0] + red1[1] + red1[2] + red1[3];
        s2 = red2[0] + red2[1] + red2[2] + red2[3];
        float m = s1 * (1.0f / CTX);
        float var = s2 * (1.0f / CTX) - m * m;
        float sd = sqrtf(var + EPS);
        int c = bc & 7;
        float w = rw[c], bb = rb[c];
        float inv_sd_w = w / sd;
#pragma unroll
        for (int k = 0; k < 4; k++) szn[tid * 4 + k] = (zv[k] - m) * inv_sd_w + bb;
        if (pb == 0) {
            if (tid < TGT) outp[bc * TGT + tid] = (bhv[tid] - bb) / (w + EPS * EPS) * sd + m;
            if (tid == 0) scalef[bc] = sd / (w + EPS * EPS);
        }
        __syncthreads();
#pragma unroll
        for (int pi = 0; pi < 4; pi++) {
            int p = pb * 4 + pi, d = tid;
            float acc;
            if (p < NF) {
                acc = bfv[d];
                int base = p * 4;
#pragma unroll
                for (int q = 0; q < 8; q++)
                    acc += szn[min(base + q, CTX - 1)] * Wf[q * DM + d];
            } else {
                acc = bcv[d];
                int base = (p - NF) * 16;
#pragma unroll
                for (int q = 0; q < 32; q++)
                    acc += szn[min(base + q, CTX - 1)] * Wc[q * DM + d];
            }
            acc += Wpos[p * DM + d];
            u[((size_t)bc * TOTAL + p) * DM + d] = f2b(acc);
        }
    }
}

// ---------------- bf16 MFMA GEMM, 64x64 tile, 2-phase double-buffered ----------------
// QKV=1: C-write goes to PER-HEAD planes: Q/K -> C + {0,1}*M*DM, V -> C2; index [h][M][16].
template <int GELU, int QKV>
__global__ __launch_bounds__(256) void k_gemm_mfma(const ushort* __restrict__ A,
                                                   const ushort* __restrict__ Wt,
                                                   const float* __restrict__ b0,
                                                   const float* __restrict__ b1,
                                                   const float* __restrict__ b2,
                                                   ushort* __restrict__ C,
                                                   ushort* __restrict__ C2,
                                                   int Mm, int N, int K) {
    __shared__ ushort As[2][64][32];
    __shared__ ushort Bs[2][64][32];
    int tid = threadIdx.x;
    int wave = tid >> 6, lane = tid & 63;
    int quad = lane >> 4, l16 = lane & 15;
    int m0 = blockIdx.y * 64, n0 = blockIdx.x * 64;

    f32x4 acc[4];
#pragma unroll
    for (int nt = 0; nt < 4; nt++) acc[nt] = (f32x4){0.f, 0.f, 0.f, 0.f};

    int srow = wave * 16 + (lane >> 2);
    int sc = (lane & 3) ^ ((srow >> 1) & 3);
    const ushort* Ag = &A[(size_t)(m0 + srow) * K + sc * 8];
    const ushort* Bg = &Wt[(size_t)(n0 + srow) * K + sc * 8];
    int rchunk = (quad ^ ((l16 >> 1) & 3)) * 8;

    ldst16(Ag, &As[0][wave * 16][0]);
    ldst16(Bg, &Bs[0][wave * 16][0]);
    PIPE_BARRIER();

    int nstep = K >> 5;
    int cur = 0;
    for (int t = 0; t < nstep; t++) {
        if (t + 1 < nstep) {
            ldst16(Ag + (t + 1) * 32, &As[cur ^ 1][wave * 16][0]);
            ldst16(Bg + (t + 1) * 32, &Bs[cur ^ 1][wave * 16][0]);
        }
        short8 af = *(const short8*)&As[cur][wave * 16 + l16][rchunk];
#pragma unroll
        for (int nt = 0; nt < 4; nt++) {
            short8 bf = *(const short8*)&Bs[cur][nt * 16 + l16][rchunk];
            acc[nt] = __builtin_amdgcn_mfma_f32_16x16x32_bf16(af, bf, acc[nt], 0, 0, 0);
        }
        PIPE_BARRIER();
        cur ^= 1;
    }
#pragma unroll
    for (int nt = 0; nt < 4; nt++) {
        int col = n0 + nt * 16 + l16;
        float bi;
        if (QKV) {
            int bs = (n0 + nt * 16) >> 8;
            const float* bp = bs == 0 ? b0 : (bs == 1 ? b1 : b2);
            bi = bp[col & 255];
        } else {
            bi = b0[col];
        }
#pragma unroll
        for (int r = 0; r < 4; r++) {
            int rowm = m0 + wave * 16 + quad * 4 + r;
            float vv = acc[nt][r] + bi;
            if (GELU) vv = vv * 0.5f * (1.0f + erff(vv * 0.70710678118f));
            if (QKV) {
                int bs = col >> 8;
                int c = col & 255, hh = c >> 4, d = c & 15;
                ushort* dst = (bs == 2) ? C2 : (C + (size_t)bs * (M * DM));
                dst[(size_t)hh * (M * DK) + (size_t)rowm * DK + d] = f2b(vv);
            } else {
                C[(size_t)rowm * N + col] = f2b(vv);
            }
        }
    }
}

// ---------------- GEMM(16x256) + bias + residual + LayerNorm, 2-phase pipelined ----------------
__global__ __launch_bounds__(256) void k_gemm_ln16(const ushort* __restrict__ A,
                                                   const ushort* __restrict__ Wt,
                                                   const float* __restrict__ bias,
                                                   const float* __restrict__ ls,
                                                   const float* __restrict__ lb,
                                                   ushort* __restrict__ u, int K) {
    __shared__ ushort As[2][16][32];
    __shared__ ushort Bs[2][256][32];
    __shared__ float ps1[16][4], ps2[16][4];
    int tid = threadIdx.x;
    int wave = tid >> 6, lane = tid & 63;
    int quad = lane >> 4, l16 = lane & 15;
    int m0 = blockIdx.x * 16;

    f32x4 acc[4];
#pragma unroll
    for (int nt = 0; nt < 4; nt++) acc[nt] = (f32x4){0.f, 0.f, 0.f, 0.f};

    int brow = wave * 16 + (lane >> 2);
    int bc_swz = (lane & 3) ^ ((brow >> 1) & 3);
    const ushort* Bg0 = &Wt[(size_t)brow * K + bc_swz * 8];
    int ar = lane >> 2;
    int ac = (lane & 3) ^ ((ar >> 1) & 3);
    const ushort* Ag = &A[(size_t)(m0 + ar) * K + ac * 8];
    int rchunk = (quad ^ ((l16 >> 1) & 3)) * 8;

    if (tid < 64) ldst16(Ag, &As[0][0][0]);
#pragma unroll
    for (int i = 0; i < 4; i++)
        ldst16(Bg0 + (size_t)i * 64 * K, &Bs[0][i * 64 + wave * 16][0]);
    PIPE_BARRIER();

    int nstep = K >> 5;
    int cur = 0;
    for (int t = 0; t < nstep; t++) {
        if (t + 1 < nstep) {
            if (tid < 64) ldst16(Ag + (t + 1) * 32, &As[cur ^ 1][0][0]);
#pragma unroll
            for (int i = 0; i < 4; i++)
                ldst16(Bg0 + (size_t)i * 64 * K + (t + 1) * 32, &Bs[cur ^ 1][i * 64 + wave * 16][0]);
        }
        short8 af = *(const short8*)&As[cur][l16][rchunk];
#pragma unroll
        for (int nt = 0; nt < 4; nt++) {
            short8 bf = *(const short8*)&Bs[cur][wave * 64 + nt * 16 + l16][rchunk];
            acc[nt] = __builtin_amdgcn_mfma_f32_16x16x32_bf16(af, bf, acc[nt], 0, 0, 0);
        }
        PIPE_BARRIER();
        cur ^= 1;
    }
    float xv[4][4];
#pragma unroll
    for (int r = 0; r < 4; r++) {
        int rowg = m0 + quad * 4 + r;
        float s1 = 0.f, s2 = 0.f;
#pragma unroll
        for (int nt = 0; nt < 4; nt++) {
            int col = wave * 64 + nt * 16 + l16;
            float x = acc[nt][r] + bias[col] + bu2f(u[(size_t)rowg * DM + col]);
            xv[r][nt] = x; s1 += x; s2 += x * x;
        }
        s1 += __shfl_xor(s1, 1); s2 += __shfl_xor(s2, 1);
        s1 += __shfl_xor(s1, 2); s2 += __shfl_xor(s2, 2);
        s1 += __shfl_xor(s1, 4); s2 += __shfl_xor(s2, 4);
        s1 += __shfl_xor(s1, 8); s2 += __shfl_xor(s2, 8);
        if (l16 == 0) { ps1[quad * 4 + r][wave] = s1; ps2[quad * 4 + r][wave] = s2; }
    }
    __syncthreads();
#pragma unroll
    for (int r = 0; r < 4; r++) {
        int rowl = quad * 4 + r, rowg = m0 + rowl;
        float s1 = ps1[rowl][0] + ps1[rowl][1] + ps1[rowl][2] + ps1[rowl][3];
        float s2 = ps2[rowl][0] + ps2[rowl][1] + ps2[rowl][2] + ps2[rowl][3];
        float m = s1 * (1.0f / DM);
        float var = s2 * (1.0f / DM) - m * m;
        float rs = rsqrtf(var + EPS);
#pragma unroll
        for (int nt = 0; nt < 4; nt++) {
            int col = wave * 64 + nt * 16 + l16;
            u[(size_t)rowg * DM + col] = f2b((xv[r][nt] - m) * rs * ls[col] + lb[col]);
        }
    }
}

// ---------------- MFMA fused attention: per-head Q/K/V layout (coalesced staging) ----------------
// qk: [layer][{Q,K}][h][M][16]; vm: [h][M][16]; ao: [M][256] (consumed by ln16).
__global__ __launch_bounds__(256, 4) void k_attn(const ushort* __restrict__ qk, const ushort* __restrict__ vm,
                                                 ushort* __restrict__ ao, int nj) {
    __shared__ ushort sh[15360];
    uint* sh32 = (uint*)sh;
    int bh = blockIdx.x, b = bh >> 4, h = bh & 15;
    int i0 = blockIdx.y * 64;
    int t = threadIdx.x, wave = t >> 6, lane = t & 63, quad = lane >> 4, l16 = lane & 15;
    const short8 zero8 = (short8){0, 0, 0, 0, 0, 0, 0, 0};
    size_t hplane = (size_t)h * (M * DK) + (size_t)b * TOTAL * DK;

    f32x4 acc[20];
#pragma unroll
    for (int nt = 0; nt < 20; nt++) acc[nt] = (f32x4){0.f, 0.f, 0.f, 0.f};

    // stage V (contiguous per-head plane): rows j, j+1 are 32B apart -> coalesced
    for (int idx = t; idx < 320; idx += 256) {
        int jp = idx >> 1, dh = idx & 1;
        int j = jp * 2;
        uint4 a = *(const uint4*)&vm[hplane + (size_t)j * DK + dh * 8];
        uint4 bb = *(const uint4*)&vm[hplane + (size_t)(j + 1) * DK + dh * 8];
        const ushort* ap = (const ushort*)&a;
        const ushort* bp = (const ushort*)&bb;
        int jr = j & 31;
        int q = (jr & 15) >> 2, jj = ((jr >> 4) << 2) + (jr & 3);
        int base = 10240 + ((j >> 5) * 4 + q) * 128 + jj;
#pragma unroll
        for (int dd = 0; dd < 8; dd++) {
            int d = dh * 8 + dd;
            uint val = (uint)ap[dd] | ((uint)bp[dd] << 16);
            sh32[(base + d * 8) >> 1] = val;
        }
    }

    for (int jl = 0; jl < nj; jl++) {
        const ushort* qm = qk + (size_t)(2 * jl) * M * DM;
        const ushort* km = qm + (size_t)M * DM;
        int kb = (jl & 1) * 5120;
        // contiguous: addr = hplane + idx*8 (idx = j*2+half) -> fully coalesced
        for (int idx = t; idx < 640; idx += 256) {
            int j = idx >> 1, half = idx & 1;
            short8 kv = *(const short8*)&km[hplane + (size_t)idx * 8];
            int jt = j >> 4, jln = j & 15;
            *(short8*)&sh[kb + ((jt * 2 + half) * 16 + jln) * 8] = kv;
        }
        short8 qf = zero8;
        if (quad < 2) qf = *(const short8*)&qm[hplane + (size_t)(i0 + wave * 16 + l16) * DK + quad * 8];
        __syncthreads();
#pragma unroll
        for (int nt = 0; nt < 20; nt++) {
            short8 kf = *(const short8*)&sh[kb + ((nt * 2 + (quad & 1)) * 16 + l16) * 8];
            acc[nt] = __builtin_amdgcn_mfma_f32_16x16x32_bf16(kf, qf, acc[nt], 0, 0, 0);
        }
    }

    float mx = -1e30f;
#pragma unroll
    for (int nt = 0; nt < 20; nt++)
#pragma unroll
        for (int r = 0; r < 4; r++) { acc[nt][r] *= SCALE; mx = fmaxf(mx, acc[nt][r]); }
    mx = fmaxf(mx, __shfl_xor(mx, 16));
    mx = fmaxf(mx, __shfl_xor(mx, 32));
    float sum = 0.f;
#pragma unroll
    for (int nt = 0; nt < 20; nt++)
#pragma unroll
        for (int r = 0; r < 4; r++) { acc[nt][r] = __expf(acc[nt][r] - mx); sum += acc[nt][r]; }
    sum += __shfl_xor(sum, 16);
    sum += __shfl_xor(sum, 32);
    float inv = 1.f / sum;
#pragma unroll
    for (int nt = 0; nt < 20; nt++)
#pragma unroll
        for (int r = 0; r < 4; r++) acc[nt][r] *= inv;

    f32x4 oacc = (f32x4){0.f, 0.f, 0.f, 0.f};
#pragma unroll
    for (int jt2 = 0; jt2 < 10; jt2++) {
        short8 vt = *(const short8*)&sh[10240 + ((jt2 * 4 + quad) * 16 + l16) * 8];
        union { short8 v; uint u[4]; } pf;
        pf.u[0] = pack2(acc[2 * jt2][0], acc[2 * jt2][1]);
        pf.u[1] = pack2(acc[2 * jt2][2], acc[2 * jt2][3]);
        pf.u[2] = pack2(acc[2 * jt2 + 1][0], acc[2 * jt2 + 1][1]);
        pf.u[3] = pack2(acc[2 * jt2 + 1][2], acc[2 * jt2 + 1][3]);
        oacc = __builtin_amdgcn_mfma_f32_16x16x32_bf16(vt, pf.v, oacc, 0, 0, 0);
    }
    us4 ov4 = (us4){f2b(oacc[0]), f2b(oacc[1]), f2b(oacc[2]), f2b(oacc[3])};
    *(us4*)&ao[((size_t)b * TOTAL + i0 + wave * 16 + l16) * DM + h * DK + quad * 4] = ov4;
}

// ---------------- head GEMM: MFMA split-K, atomic accumulate into pre-initialized out ----------------
__global__ __launch_bounds__(256) void k_head(const ushort* __restrict__ u, const ushort* __restrict__ WhT2,
                                              const float* __restrict__ scalef, float* __restrict__ out) {
    int t0 = blockIdx.x * 16;
    int wave = threadIdx.x >> 6, lane = threadIdx.x & 63;
    int quad = lane >> 4, l16 = lane & 15;
    int chunk = blockIdx.y * 4 + wave;
    int kbeg = chunk * 1024;
    f32x4 acc = (f32x4){0.f, 0.f, 0.f, 0.f};
    const ushort* za = &u[(size_t)l16 * KHEAD + quad * 8];
    const ushort* wb = &WhT2[(size_t)(t0 + l16) * KHEAD + quad * 8];
#pragma unroll 4
    for (int k = kbeg; k < kbeg + 1024; k += 32) {
        short8 af = *(const short8*)&za[k];
        short8 bf = *(const short8*)&wb[k];
        acc = __builtin_amdgcn_mfma_f32_16x16x32_bf16(af, bf, acc, 0, 0, 0);
    }
#pragma unroll
    for (int r = 0; r < 4; r++) {
        int bcr = quad * 4 + r;
        atomicAdd(&out[bcr * TGT + t0 + l16], acc[r] * scalef[bcr]);
    }
}

extern "C" void kernel_launch(void* const* d_in, const int* in_sizes, int n_in,
                              void* d_out, int out_size, void* d_ws, size_t ws_size,
                              hipStream_t stream) {
    const float* z       = (const float*)d_in[0];
    const float* revin_w = (const float*)d_in[1];
    const float* revin_b = (const float*)d_in[2];
    const float* Wf      = (const float*)d_in[3];
    const float* bfv     = (const float*)d_in[4];
    const float* Wc      = (const float*)d_in[5];
    const float* bcv     = (const float*)d_in[6];
    const float* Wpos    = (const float*)d_in[7];
    const float* WQ      = (const float*)d_in[8];
    const float* bQ      = (const float*)d_in[9];
    const float* WK      = (const float*)d_in[10];
    const float* bK      = (const float*)d_in[11];
    const float* WV      = (const float*)d_in[12];
    const float* bV      = (const float*)d_in[13];
    const float* WO      = (const float*)d_in[14];
    const float* bO      = (const float*)d_in[15];
    const float* ln1s    = (const float*)d_in[16];
    const float* ln1b    = (const float*)d_in[17];
    const float* ln2s    = (const float*)d_in[18];
    const float* ln2b    = (const float*)d_in[19];
    const float* F1      = (const float*)d_in[20];
    const float* c1      = (const float*)d_in[21];
    const float* F2      = (const float*)d_in[22];
    const float* c2      = (const float*)d_in[23];
    const float* Wh      = (const float*)d_in[24];
    const float* bh      = (const float*)d_in[25];
    float* out = (float*)d_out;

    char* p = (char*)d_ws;
    float* scalef = (float*)p;   p += 16 * 4;
    p = (char*)(((size_t)p + 255) & ~255ull);
    ushort* u     = (ushort*)p;  p += (size_t)M * DM * 2;
    ushort* qkbuf = (ushort*)p;  p += (size_t)NL * 2 * M * DM * 2;   // per-layer [Q,K] per-head planes
    ushort* vbuf  = (ushort*)p;  p += (size_t)M * DM * 2;            // V per-head planes
    ushort* ax    = (ushort*)p;  p += (size_t)M * DM * 2;
    ushort* hbuf  = (ushort*)p;  p += (size_t)M * DFF * 2;
    ushort* Wtqkv = (ushort*)p;  p += (size_t)NL * 768 * 256 * 2;
    ushort* WtO   = (ushort*)p;  p += (size_t)NL * 256 * 256 * 2;
    ushort* Ft1   = (ushort*)p;  p += (size_t)NL * 1024 * 256 * 2;
    ushort* Ft2   = (ushort*)p;  p += (size_t)NL * 256 * 1024 * 2;
    ushort* WhT2  = (ushort*)p;  p += (size_t)TGT * KHEAD * 2;

    k_prep<<<3328, 256, 0, stream>>>(WQ, WK, WV, WO, F1, F2, Wh,
                                     Wtqkv, WtO, Ft1, Ft2, WhT2,
                                     z, revin_w, revin_b,
                                     Wf, bfv, Wc, bcv, Wpos, u,
                                     bh, out, scalef);

    for (int l = 0; l < NL; l++) {
        k_gemm_mfma<0, 1><<<dim3(12, 80), 256, 0, stream>>>(
            u, Wtqkv + (size_t)l * 768 * 256, bQ + l * DM, bK + l * DM, bV + l * DM,
            qkbuf + (size_t)l * 2 * M * DM, vbuf, M, 768, 256);
        k_attn<<<dim3(NB * NH, 5), 256, 0, stream>>>(qkbuf, vbuf, ax, l + 1);
        k_gemm_ln16<<<M / 16, 256, 0, stream>>>(
            ax, WtO + (size_t)l * 65536, bO + l * DM, ln1s + l * DM, ln1b + l * DM, u, 256);
        k_gemm_mfma<1, 0><<<dim3(16, 80), 256, 0, stream>>>(
            u, Ft1 + (size_t)l * 262144, c1 + l * DFF, c1, c1, hbuf, hbuf, M, 1024, 256);
        k_gemm_ln16<<<M / 16, 256, 0, stream>>>(
            hbuf, Ft2 + (size_t)l * 262144, c2 + l * DM, ln2s + l * DM, ln2b + l * DM, u, 1024);
    }

    k_head<<<dim3(TGT / 16, 20), 256, 0, stream>>>(u, WhT2, scalef, out);
}

// Round 10
// 426.121 us; speedup vs baseline: 1.2737x; 1.0038x over previous
//
#include <hip/hip_runtime.h>
#include <math.h>

typedef unsigned short ushort;
typedef unsigned int uint;
typedef __attribute__((ext_vector_type(8))) short short8;
typedef __attribute__((ext_vector_type(4))) float f32x4;
typedef __attribute__((ext_vector_type(4))) ushort us4;

constexpr int BS = 2, C_IN = 8, CTX = 1024, TGT = 96;
constexpr int DM = 256, NH = 16, DFF = 1024, NL = 4;
constexpr int NF = 256, TOTAL = 320;
constexpr int NB = 16;
constexpr int DK = 16;
constexpr float EPS = 1e-5f;
constexpr float SCALE = 0.25f;
constexpr int KHEAD = DM * TOTAL;  // 81920
constexpr int M = NB * TOTAL;      // 5120

__device__ __forceinline__ ushort f2b(float x) {
    uint u = __float_as_uint(x);
    u += 0x7fff + ((u >> 16) & 1);
    return (ushort)(u >> 16);
}
__device__ __forceinline__ float bu2f(ushort x) { return __uint_as_float(((uint)x) << 16); }
__device__ __forceinline__ uint pack2(float a, float b) { return (uint)f2b(a) | ((uint)f2b(b) << 16); }

typedef __attribute__((address_space(3))) uint lds_u32;
typedef const __attribute__((address_space(1))) uint glb_u32;
__device__ __forceinline__ void ldst16(const void* g, void* l) {
    __builtin_amdgcn_global_load_lds((glb_u32*)g, (lds_u32*)l, 16, 0, 0);
}

#define PIPE_BARRIER() asm volatile("s_waitcnt vmcnt(0)\n\ts_barrier" ::: "memory")

// ---------------- prep v2: vectorized weight transposes + RevIN + embed + out-init ----------------
__global__ __launch_bounds__(256) void k_prep(
        const float* __restrict__ WQ, const float* __restrict__ WK,
        const float* __restrict__ WV, const float* __restrict__ WO,
        const float* __restrict__ F1, const float* __restrict__ F2,
        const float* __restrict__ Wh,
        ushort* __restrict__ Wtqkv, ushort* __restrict__ WtO,
        ushort* __restrict__ Ft1, ushort* __restrict__ Ft2,
        ushort* __restrict__ WhT2,
        const float* __restrict__ z, const float* __restrict__ rw,
        const float* __restrict__ rb,
        const float* __restrict__ Wf, const float* __restrict__ bfv,
        const float* __restrict__ Wc, const float* __restrict__ bcv,
        const float* __restrict__ Wpos, ushort* __restrict__ u,
        const float* __restrict__ bhv, float* __restrict__ outp,
        float* __restrict__ scalef) {
    __shared__ __align__(16) ushort tile[64 * 98];
    __shared__ float szn[CTX];
    __shared__ float red1[4], red2[4];
    int i = blockIdx.x, tid = threadIdx.x;

    if (i < 768) {
        const float* src; ushort* dst; int lsrc, ldst_, r0, c0;
        if (i < 256) {
            int mat = i >> 4, l = mat >> 2, w = mat & 3;
            src = (w == 0 ? WQ : (w == 1 ? WK : (w == 2 ? WV : WO))) + l * 65536;
            dst = (w < 3) ? (Wtqkv + (size_t)l * 768 * 256 + w * 65536)
                          : (WtO + (size_t)l * 65536);
            lsrc = 256; ldst_ = 256; r0 = ((i >> 2) & 3) * 64; c0 = (i & 3) * 64;
        } else if (i < 512) {
            int j = i - 256, l = j >> 6, t = j & 63;
            src = F1 + (size_t)l * 262144; dst = Ft1 + (size_t)l * 262144;
            lsrc = 1024; ldst_ = 256; r0 = (t >> 4) * 64; c0 = (t & 15) * 64;
        } else {
            int j = i - 512, l = j >> 6, t = j & 63;
            src = F2 + (size_t)l * 262144; dst = Ft2 + (size_t)l * 262144;
            lsrc = 256; ldst_ = 1024; r0 = (t >> 2) * 64; c0 = (t & 3) * 64;
        }
#pragma unroll
        for (int it = 0; it < 4; it++) {
            int fid = it * 256 + tid;
            int fr = fid >> 4, fc = fid & 15;
            f32x4 v = *(const f32x4*)&src[(size_t)(r0 + fr) * lsrc + c0 + fc * 4];
            ushort* tr = &tile[fr * 66];
            tr[fc * 4 + 0] = f2b(v[0]); tr[fc * 4 + 1] = f2b(v[1]);
            tr[fc * 4 + 2] = f2b(v[2]); tr[fc * 4 + 3] = f2b(v[3]);
        }
        __syncthreads();
#pragma unroll
        for (int it = 0; it < 4; it++) {
            int sid = it * 256 + tid;
            int cr = sid >> 4, cc = sid & 15;
            us4 v = (us4){ tile[(cc * 4 + 0) * 66 + cr], tile[(cc * 4 + 1) * 66 + cr],
                           tile[(cc * 4 + 2) * 66 + cr], tile[(cc * 4 + 3) * 66 + cr] };
            *(us4*)&dst[(size_t)(c0 + cr) * ldst_ + r0 + cc * 4] = v;
        }
    } else if (i < 2048) {
        int j = i - 768;
        int pp = j >> 2, d0 = (j & 3) * 64;
#pragma unroll
        for (int it = 0; it < 6; it++) {
            int fid = it * 256 + tid;
            int fr = fid / 24, fc = fid % 24;
            f32x4 v = *(const f32x4*)&Wh[((size_t)(d0 + fr) * 320 + pp) * 96 + fc * 4];
            ushort* tr = &tile[fr * 98];
            tr[fc * 4 + 0] = f2b(v[0]); tr[fc * 4 + 1] = f2b(v[1]);
            tr[fc * 4 + 2] = f2b(v[2]); tr[fc * 4 + 3] = f2b(v[3]);
        }
        __syncthreads();
#pragma unroll
        for (int it = 0; it < 6; it++) {
            int sid = it * 256 + tid;
            int tr = sid >> 4, dc = sid & 15;
            us4 v = (us4){ tile[(dc * 4 + 0) * 98 + tr], tile[(dc * 4 + 1) * 98 + tr],
                           tile[(dc * 4 + 2) * 98 + tr], tile[(dc * 4 + 3) * 98 + tr] };
            *(us4*)&WhT2[(size_t)tr * KHEAD + pp * 256 + d0 + dc * 4] = v;
        }
    } else {
        int j = i - 2048;
        int bc = j / 80, pb = j % 80;
        int wave = tid >> 6, lane = tid & 63;
        f32x4 zv = *(const f32x4*)&z[bc * CTX + tid * 4];
        float s1 = zv[0] + zv[1] + zv[2] + zv[3];
        float s2 = zv[0] * zv[0] + zv[1] * zv[1] + zv[2] * zv[2] + zv[3] * zv[3];
#pragma unroll
        for (int off = 1; off < 64; off <<= 1) {
            s1 += __shfl_xor(s1, off);
            s2 += __shfl_xor(s2, off);
        }
        if (lane == 0) { red1[wave] = s1; red2[wave] = s2; }
        __syncthreads();
        s1 = red1[0] + red1[1] + red1[2] + red1[3];
        s2 = red2[0] + red2[1] + red2[2] + red2[3];
        float m = s1 * (1.0f / CTX);
        float var = s2 * (1.0f / CTX) - m * m;
        float sd = sqrtf(var + EPS);
        int c = bc & 7;
        float w = rw[c], bb = rb[c];
        float inv_sd_w = w / sd;
#pragma unroll
        for (int k = 0; k < 4; k++) szn[tid * 4 + k] = (zv[k] - m) * inv_sd_w + bb;
        if (pb == 0) {
            if (tid < TGT) outp[bc * TGT + tid] = (bhv[tid] - bb) / (w + EPS * EPS) * sd + m;
            if (tid == 0) scalef[bc] = sd / (w + EPS * EPS);
        }
        __syncthreads();
#pragma unroll
        for (int pi = 0; pi < 4; pi++) {
            int p = pb * 4 + pi, d = tid;
            float acc;
            if (p < NF) {
                acc = bfv[d];
                int base = p * 4;
#pragma unroll
                for (int q = 0; q < 8; q++)
                    acc += szn[min(base + q, CTX - 1)] * Wf[q * DM + d];
            } else {
                acc = bcv[d];
                int base = (p - NF) * 16;
#pragma unroll
                for (int q = 0; q < 32; q++)
                    acc += szn[min(base + q, CTX - 1)] * Wc[q * DM + d];
            }
            acc += Wpos[p * DM + d];
            u[((size_t)bc * TOTAL + p) * DM + d] = f2b(acc);
        }
    }
}

// ---------------- bf16 MFMA GEMM, 64x64 tile, 2-phase double-buffered ----------------
// QKV=1: Q -> linear per-head plane; K -> perm_k attention-LDS-image; V -> perm_v image.
template <int GELU, int QKV>
__global__ __launch_bounds__(256) void k_gemm_mfma(const ushort* __restrict__ A,
                                                   const ushort* __restrict__ Wt,
                                                   const float* __restrict__ b0,
                                                   const float* __restrict__ b1,
                                                   const float* __restrict__ b2,
                                                   ushort* __restrict__ C,
                                                   ushort* __restrict__ C2,
                                                   int Mm, int N, int K) {
    __shared__ ushort As[2][64][32];
    __shared__ ushort Bs[2][64][32];
    int tid = threadIdx.x;
    int wave = tid >> 6, lane = tid & 63;
    int quad = lane >> 4, l16 = lane & 15;
    int m0 = blockIdx.y * 64, n0 = blockIdx.x * 64;

    f32x4 acc[4];
#pragma unroll
    for (int nt = 0; nt < 4; nt++) acc[nt] = (f32x4){0.f, 0.f, 0.f, 0.f};

    int srow = wave * 16 + (lane >> 2);
    int sc = (lane & 3) ^ ((srow >> 1) & 3);
    const ushort* Ag = &A[(size_t)(m0 + srow) * K + sc * 8];
    const ushort* Bg = &Wt[(size_t)(n0 + srow) * K + sc * 8];
    int rchunk = (quad ^ ((l16 >> 1) & 3)) * 8;

    ldst16(Ag, &As[0][wave * 16][0]);
    ldst16(Bg, &Bs[0][wave * 16][0]);
    PIPE_BARRIER();

    int nstep = K >> 5;
    int cur = 0;
    for (int t = 0; t < nstep; t++) {
        if (t + 1 < nstep) {
            ldst16(Ag + (t + 1) * 32, &As[cur ^ 1][wave * 16][0]);
            ldst16(Bg + (t + 1) * 32, &Bs[cur ^ 1][wave * 16][0]);
        }
        short8 af = *(const short8*)&As[cur][wave * 16 + l16][rchunk];
#pragma unroll
        for (int nt = 0; nt < 4; nt++) {
            short8 bf = *(const short8*)&Bs[cur][nt * 16 + l16][rchunk];
            acc[nt] = __builtin_amdgcn_mfma_f32_16x16x32_bf16(af, bf, acc[nt], 0, 0, 0);
        }
        PIPE_BARRIER();
        cur ^= 1;
    }
#pragma unroll
    for (int nt = 0; nt < 4; nt++) {
        int col = n0 + nt * 16 + l16;
        float bi;
        if (QKV) {
            int bs = (n0 + nt * 16) >> 8;
            const float* bp = bs == 0 ? b0 : (bs == 1 ? b1 : b2);
            bi = bp[col & 255];
        } else {
            bi = b0[col];
        }
#pragma unroll
        for (int r = 0; r < 4; r++) {
            int rowm = m0 + wave * 16 + quad * 4 + r;
            float vv = acc[nt][r] + bi;
            if (GELU) vv = vv * 0.5f * (1.0f + erff(vv * 0.70710678118f));
            if (QKV) {
                int bs = col >> 8;
                int c = col & 255, hh = c >> 4, d = c & 15;
                int bb = rowm / 320, j = rowm - bb * 320;
                size_t plane = (size_t)hh * (M * DK) + (size_t)bb * (TOTAL * DK);
                if (bs == 0) {
                    C[plane + (size_t)j * DK + d] = f2b(vv);
                } else if (bs == 1) {
                    int off = (((j >> 4) * 2 + (d >> 3)) * 16 + (j & 15)) * 8 + (d & 7);
                    C[(size_t)M * DM + plane + off] = f2b(vv);
                } else {
                    int off = ((j >> 5) * 4 + ((j & 15) >> 2)) * 128 +
                              (((j >> 4) & 1) << 2) + (j & 3) + d * 8;
                    C2[plane + off] = f2b(vv);
                }
            } else {
                C[(size_t)rowm * N + col] = f2b(vv);
            }
        }
    }
}

// ---------------- GEMM(16x256) + bias + residual + LayerNorm, 2-phase pipelined ----------------
__global__ __launch_bounds__(256) void k_gemm_ln16(const ushort* __restrict__ A,
                                                   const ushort* __restrict__ Wt,
                                                   const float* __restrict__ bias,
                                                   const float* __restrict__ ls,
                                                   const float* __restrict__ lb,
                                                   ushort* __restrict__ u, int K) {
    __shared__ ushort As[2][16][32];
    __shared__ ushort Bs[2][256][32];
    __shared__ float ps1[16][4], ps2[16][4];
    int tid = threadIdx.x;
    int wave = tid >> 6, lane = tid & 63;
    int quad = lane >> 4, l16 = lane & 15;
    int m0 = blockIdx.x * 16;

    f32x4 acc[4];
#pragma unroll
    for (int nt = 0; nt < 4; nt++) acc[nt] = (f32x4){0.f, 0.f, 0.f, 0.f};

    int brow = wave * 16 + (lane >> 2);
    int bc_swz = (lane & 3) ^ ((brow >> 1) & 3);
    const ushort* Bg0 = &Wt[(size_t)brow * K + bc_swz * 8];
    int ar = lane >> 2;
    int ac = (lane & 3) ^ ((ar >> 1) & 3);
    const ushort* Ag = &A[(size_t)(m0 + ar) * K + ac * 8];
    int rchunk = (quad ^ ((l16 >> 1) & 3)) * 8;

    if (tid < 64) ldst16(Ag, &As[0][0][0]);
#pragma unroll
    for (int i = 0; i < 4; i++)
        ldst16(Bg0 + (size_t)i * 64 * K, &Bs[0][i * 64 + wave * 16][0]);
    PIPE_BARRIER();

    int nstep = K >> 5;
    int cur = 0;
    for (int t = 0; t < nstep; t++) {
        if (t + 1 < nstep) {
            if (tid < 64) ldst16(Ag + (t + 1) * 32, &As[cur ^ 1][0][0]);
#pragma unroll
            for (int i = 0; i < 4; i++)
                ldst16(Bg0 + (size_t)i * 64 * K + (t + 1) * 32, &Bs[cur ^ 1][i * 64 + wave * 16][0]);
        }
        short8 af = *(const short8*)&As[cur][l16][rchunk];
#pragma unroll
        for (int nt = 0; nt < 4; nt++) {
            short8 bf = *(const short8*)&Bs[cur][wave * 64 + nt * 16 + l16][rchunk];
            acc[nt] = __builtin_amdgcn_mfma_f32_16x16x32_bf16(af, bf, acc[nt], 0, 0, 0);
        }
        PIPE_BARRIER();
        cur ^= 1;
    }
    float xv[4][4];
#pragma unroll
    for (int r = 0; r < 4; r++) {
        int rowg = m0 + quad * 4 + r;
        float s1 = 0.f, s2 = 0.f;
#pragma unroll
        for (int nt = 0; nt < 4; nt++) {
            int col = wave * 64 + nt * 16 + l16;
            float x = acc[nt][r] + bias[col] + bu2f(u[(size_t)rowg * DM + col]);
            xv[r][nt] = x; s1 += x; s2 += x * x;
        }
        s1 += __shfl_xor(s1, 1); s2 += __shfl_xor(s2, 1);
        s1 += __shfl_xor(s1, 2); s2 += __shfl_xor(s2, 2);
        s1 += __shfl_xor(s1, 4); s2 += __shfl_xor(s2, 4);
        s1 += __shfl_xor(s1, 8); s2 += __shfl_xor(s2, 8);
        if (l16 == 0) { ps1[quad * 4 + r][wave] = s1; ps2[quad * 4 + r][wave] = s2; }
    }
    __syncthreads();
#pragma unroll
    for (int r = 0; r < 4; r++) {
        int rowl = quad * 4 + r, rowg = m0 + rowl;
        float s1 = ps1[rowl][0] + ps1[rowl][1] + ps1[rowl][2] + ps1[rowl][3];
        float s2 = ps2[rowl][0] + ps2[rowl][1] + ps2[rowl][2] + ps2[rowl][3];
        float m = s1 * (1.0f / DM);
        float var = s2 * (1.0f / DM) - m * m;
        float rs = rsqrtf(var + EPS);
#pragma unroll
        for (int nt = 0; nt < 4; nt++) {
            int col = wave * 64 + nt * 16 + l16;
            u[(size_t)rowg * DM + col] = f2b((xv[r][nt] - m) * rs * ls[col] + lb[col]);
        }
    }
}

// ---------------- attention v8: all-DMA staging (pre-permuted K/V), ONE barrier, no per-slot sync ----
// LDS: K slots s*5120 (s=0..3), V at 20480. qk: [layer][{Q,K}][h][b][...]; K/V pre-permuted.
__global__ __launch_bounds__(256, 3) void k_attn(const ushort* __restrict__ qk, const ushort* __restrict__ vm,
                                                 ushort* __restrict__ ao, int nj) {
    __shared__ __align__(16) ushort sh[25600];
    int bh = blockIdx.x, b = bh >> 4, h = bh & 15;
    int i0 = blockIdx.y * 64;
    int t = threadIdx.x, wave = t >> 6, lane = t & 63, quad = lane >> 4, l16 = lane & 15;
    const short8 zero8 = (short8){0, 0, 0, 0, 0, 0, 0, 0};
    size_t hplane = (size_t)h * (M * DK) + (size_t)b * (TOTAL * DK);

    // DMA staging: nj K slots + V, 10 wave-chunks each (1024B per chunk)
    int nchunks = (nj + 1) * 10;
    for (int c = wave; c < nchunks; c += 4) {
        int s = c / 10, cc = c - s * 10;
        const ushort* src = (s < nj)
            ? qk + (size_t)(2 * s + 1) * (M * DM) + hplane + cc * 512
            : vm + hplane + cc * 512;
        int dstbase = (s < nj ? s * 5120 : 20480) + cc * 512;
        ldst16(src + lane * 8, &sh[dstbase]);
    }
    // Q fragments for all passes (per-lane 16B; completes under the same vmcnt drain)
    short8 qfr[4] = { zero8, zero8, zero8, zero8 };
    int qrow = i0 + wave * 16 + l16;
#pragma unroll
    for (int jl = 0; jl < 4; jl++)
        if (jl < nj && quad < 2)
            qfr[jl] = *(const short8*)&qk[(size_t)(2 * jl) * (M * DM) + hplane +
                                          (size_t)qrow * DK + quad * 8];
    PIPE_BARRIER();   // the only barrier in the kernel

    f32x4 acc[20];
#pragma unroll
    for (int nt = 0; nt < 20; nt++) acc[nt] = (f32x4){0.f, 0.f, 0.f, 0.f};

    __builtin_amdgcn_s_setprio(1);
#pragma unroll
    for (int jl = 0; jl < 4; jl++) {
        if (jl < nj) {
            int kb = jl * 5120;
#pragma unroll
            for (int nt = 0; nt < 20; nt++) {
                short8 kf = *(const short8*)&sh[kb + ((nt * 2 + (quad & 1)) * 16 + l16) * 8];
                acc[nt] = __builtin_amdgcn_mfma_f32_16x16x32_bf16(kf, qfr[jl], acc[nt], 0, 0, 0);
            }
        }
    }
    __builtin_amdgcn_s_setprio(0);

    float mx = -1e30f;
#pragma unroll
    for (int nt = 0; nt < 20; nt++)
#pragma unroll
        for (int r = 0; r < 4; r++) { acc[nt][r] *= SCALE; mx = fmaxf(mx, acc[nt][r]); }
    mx = fmaxf(mx, __shfl_xor(mx, 16));
    mx = fmaxf(mx, __shfl_xor(mx, 32));
    float sum = 0.f;
#pragma unroll
    for (int nt = 0; nt < 20; nt++)
#pragma unroll
        for (int r = 0; r < 4; r++) { acc[nt][r] = __expf(acc[nt][r] - mx); sum += acc[nt][r]; }
    sum += __shfl_xor(sum, 16);
    sum += __shfl_xor(sum, 32);
    float inv = 1.f / sum;
#pragma unroll
    for (int nt = 0; nt < 20; nt++)
#pragma unroll
        for (int r = 0; r < 4; r++) acc[nt][r] *= inv;

    f32x4 oacc = (f32x4){0.f, 0.f, 0.f, 0.f};
    __builtin_amdgcn_s_setprio(1);
#pragma unroll
    for (int jt2 = 0; jt2 < 10; jt2++) {
        short8 vt = *(const short8*)&sh[20480 + ((jt2 * 4 + quad) * 16 + l16) * 8];
        union { short8 v; uint u[4]; } pf;
        pf.u[0] = pack2(acc[2 * jt2][0], acc[2 * jt2][1]);
        pf.u[1] = pack2(acc[2 * jt2][2], acc[2 * jt2][3]);
        pf.u[2] = pack2(acc[2 * jt2 + 1][0], acc[2 * jt2 + 1][1]);
        pf.u[3] = pack2(acc[2 * jt2 + 1][2], acc[2 * jt2 + 1][3]);
        oacc = __builtin_amdgcn_mfma_f32_16x16x32_bf16(vt, pf.v, oacc, 0, 0, 0);
    }
    __builtin_amdgcn_s_setprio(0);
    us4 ov4 = (us4){f2b(oacc[0]), f2b(oacc[1]), f2b(oacc[2]), f2b(oacc[3])};
    *(us4*)&ao[((size_t)b * TOTAL + i0 + wave * 16 + l16) * DM + h * DK + quad * 4] = ov4;
}

// ---------------- head GEMM: MFMA split-K, atomic accumulate into pre-initialized out ----------------
__global__ __launch_bounds__(256) void k_head(const ushort* __restrict__ u, const ushort* __restrict__ WhT2,
                                              const float* __restrict__ scalef, float* __restrict__ out) {
    int t0 = blockIdx.x * 16;
    int wave = threadIdx.x >> 6, lane = threadIdx.x & 63;
    int quad = lane >> 4, l16 = lane & 15;
    int chunk = blockIdx.y * 4 + wave;
    int kbeg = chunk * 1024;
    f32x4 acc = (f32x4){0.f, 0.f, 0.f, 0.f};
    const ushort* za = &u[(size_t)l16 * KHEAD + quad * 8];
    const ushort* wb = &WhT2[(size_t)(t0 + l16) * KHEAD + quad * 8];
#pragma unroll 4
    for (int k = kbeg; k < kbeg + 1024; k += 32) {
        short8 af = *(const short8*)&za[k];
        short8 bf = *(const short8*)&wb[k];
        acc = __builtin_amdgcn_mfma_f32_16x16x32_bf16(af, bf, acc, 0, 0, 0);
    }
#pragma unroll
    for (int r = 0; r < 4; r++) {
        int bcr = quad * 4 + r;
        atomicAdd(&out[bcr * TGT + t0 + l16], acc[r] * scalef[bcr]);
    }
}

extern "C" void kernel_launch(void* const* d_in, const int* in_sizes, int n_in,
                              void* d_out, int out_size, void* d_ws, size_t ws_size,
                              hipStream_t stream) {
    const float* z       = (const float*)d_in[0];
    const float* revin_w = (const float*)d_in[1];
    const float* revin_b = (const float*)d_in[2];
    const float* Wf      = (const float*)d_in[3];
    const float* bfv     = (const float*)d_in[4];
    const float* Wc      = (const float*)d_in[5];
    const float* bcv     = (const float*)d_in[6];
    const float* Wpos    = (const float*)d_in[7];
    const float* WQ      = (const float*)d_in[8];
    const float* bQ      = (const float*)d_in[9];
    const float* WK      = (const float*)d_in[10];
    const float* bK      = (const float*)d_in[11];
    const float* WV      = (const float*)d_in[12];
    const float* bV      = (const float*)d_in[13];
    const float* WO      = (const float*)d_in[14];
    const float* bO      = (const float*)d_in[15];
    const float* ln1s    = (const float*)d_in[16];
    const float* ln1b    = (const float*)d_in[17];
    const float* ln2s    = (const float*)d_in[18];
    const float* ln2b    = (const float*)d_in[19];
    const float* F1      = (const float*)d_in[20];
    const float* c1      = (const float*)d_in[21];
    const float* F2      = (const float*)d_in[22];
    const float* c2      = (const float*)d_in[23];
    const float* Wh      = (const float*)d_in[24];
    const float* bh      = (const float*)d_in[25];
    float* out = (float*)d_out;

    char* p = (char*)d_ws;
    float* scalef = (float*)p;   p += 16 * 4;
    p = (char*)(((size_t)p + 255) & ~255ull);
    ushort* u     = (ushort*)p;  p += (size_t)M * DM * 2;
    ushort* qkbuf = (ushort*)p;  p += (size_t)NL * 2 * M * DM * 2;   // per-layer [Q,K] head planes
    ushort* vbuf  = (ushort*)p;  p += (size_t)M * DM * 2;            // V head planes (permuted)
    ushort* ax    = (ushort*)p;  p += (size_t)M * DM * 2;
    ushort* hbuf  = (ushort*)p;  p += (size_t)M * DFF * 2;
    ushort* Wtqkv = (ushort*)p;  p += (size_t)NL * 768 * 256 * 2;
    ushort* WtO   = (ushort*)p;  p += (size_t)NL * 256 * 256 * 2;
    ushort* Ft1   = (ushort*)p;  p += (size_t)NL * 1024 * 256 * 2;
    ushort* Ft2   = (ushort*)p;  p += (size_t)NL * 256 * 1024 * 2;
    ushort* WhT2  = (ushort*)p;  p += (size_t)TGT * KHEAD * 2;

    k_prep<<<3328, 256, 0, stream>>>(WQ, WK, WV, WO, F1, F2, Wh,
                                     Wtqkv, WtO, Ft1, Ft2, WhT2,
                                     z, revin_w, revin_b,
                                     Wf, bfv, Wc, bcv, Wpos, u,
                                     bh, out, scalef);

    for (int l = 0; l < NL; l++) {
        k_gemm_mfma<0, 1><<<dim3(12, 80), 256, 0, stream>>>(
            u, Wtqkv + (size_t)l * 768 * 256, bQ + l * DM, bK + l * DM, bV + l * DM,
            qkbuf + (size_t)l * 2 * M * DM, vbuf, M, 768, 256);
        k_attn<<<dim3(NB * NH, 5), 256, 0, stream>>>(qkbuf, vbuf, ax, l + 1);
        k_gemm_ln16<<<M / 16, 256, 0, stream>>>(
            ax, WtO + (size_t)l * 65536, bO + l * DM, ln1s + l * DM, ln1b + l * DM, u, 256);
        k_gemm_mfma<1, 0><<<dim3(16, 80), 256, 0, stream>>>(
            u, Ft1 + (size_t)l * 262144, c1 + l * DFF, c1, c1, hbuf, hbuf, M, 1024, 256);
        k_gemm_ln16<<<M / 16, 256, 0, stream>>>(
            hbuf, Ft2 + (size_t)l * 262144, c2 + l * DM, ln2s + l * DM, ln2b + l * DM, u, 1024);
    }

    k_head<<<dim3(TGT / 16, 20), 256, 0, stream>>>(u, WhT2, scalef, out);
}

// Round 11
// 419.222 us; speedup vs baseline: 1.2947x; 1.0165x over previous
//
#include <hip/hip_runtime.h>
#include <math.h>

typedef unsigned short ushort;
typedef unsigned int uint;
typedef __attribute__((ext_vector_type(8))) short short8;
typedef __attribute__((ext_vector_type(4))) float f32x4;
typedef __attribute__((ext_vector_type(4))) ushort us4;

constexpr int BS = 2, C_IN = 8, CTX = 1024, TGT = 96;
constexpr int DM = 256, NH = 16, DFF = 1024, NL = 4;
constexpr int NF = 256, TOTAL = 320;
constexpr int NB = 16;
constexpr int DK = 16;
constexpr float EPS = 1e-5f;
constexpr float SCALE = 0.25f;
constexpr int KHEAD = DM * TOTAL;  // 81920
constexpr int M = NB * TOTAL;      // 5120

__device__ __forceinline__ ushort f2b(float x) {
    uint u = __float_as_uint(x);
    u += 0x7fff + ((u >> 16) & 1);
    return (ushort)(u >> 16);
}
__device__ __forceinline__ float bu2f(ushort x) { return __uint_as_float(((uint)x) << 16); }
__device__ __forceinline__ uint pack2(float a, float b) { return (uint)f2b(a) | ((uint)f2b(b) << 16); }

typedef __attribute__((address_space(3))) uint lds_u32;
typedef const __attribute__((address_space(1))) uint glb_u32;
__device__ __forceinline__ void ldst16(const void* g, void* l) {
    __builtin_amdgcn_global_load_lds((glb_u32*)g, (lds_u32*)l, 16, 0, 0);
}

#define PIPE_BARRIER() asm volatile("s_waitcnt vmcnt(0)\n\ts_barrier" ::: "memory")

// ---------------- prep v2: vectorized weight transposes + RevIN + embed + out-init ----------------
__global__ __launch_bounds__(256) void k_prep(
        const float* __restrict__ WQ, const float* __restrict__ WK,
        const float* __restrict__ WV, const float* __restrict__ WO,
        const float* __restrict__ F1, const float* __restrict__ F2,
        const float* __restrict__ Wh,
        ushort* __restrict__ Wtqkv, ushort* __restrict__ WtO,
        ushort* __restrict__ Ft1, ushort* __restrict__ Ft2,
        ushort* __restrict__ WhT2,
        const float* __restrict__ z, const float* __restrict__ rw,
        const float* __restrict__ rb,
        const float* __restrict__ Wf, const float* __restrict__ bfv,
        const float* __restrict__ Wc, const float* __restrict__ bcv,
        const float* __restrict__ Wpos, ushort* __restrict__ u,
        const float* __restrict__ bhv, float* __restrict__ outp,
        float* __restrict__ scalef) {
    __shared__ __align__(16) ushort tile[64 * 98];
    __shared__ float szn[CTX];
    __shared__ float red1[4], red2[4];
    int i = blockIdx.x, tid = threadIdx.x;

    if (i < 768) {
        const float* src; ushort* dst; int lsrc, ldst_, r0, c0;
        if (i < 256) {
            int mat = i >> 4, l = mat >> 2, w = mat & 3;
            src = (w == 0 ? WQ : (w == 1 ? WK : (w == 2 ? WV : WO))) + l * 65536;
            dst = (w < 3) ? (Wtqkv + (size_t)l * 768 * 256 + w * 65536)
                          : (WtO + (size_t)l * 65536);
            lsrc = 256; ldst_ = 256; r0 = ((i >> 2) & 3) * 64; c0 = (i & 3) * 64;
        } else if (i < 512) {
            int j = i - 256, l = j >> 6, t = j & 63;
            src = F1 + (size_t)l * 262144; dst = Ft1 + (size_t)l * 262144;
            lsrc = 1024; ldst_ = 256; r0 = (t >> 4) * 64; c0 = (t & 15) * 64;
        } else {
            int j = i - 512, l = j >> 6, t = j & 63;
            src = F2 + (size_t)l * 262144; dst = Ft2 + (size_t)l * 262144;
            lsrc = 256; ldst_ = 1024; r0 = (t >> 2) * 64; c0 = (t & 3) * 64;
        }
#pragma unroll
        for (int it = 0; it < 4; it++) {
            int fid = it * 256 + tid;
            int fr = fid >> 4, fc = fid & 15;
            f32x4 v = *(const f32x4*)&src[(size_t)(r0 + fr) * lsrc + c0 + fc * 4];
            ushort* tr = &tile[fr * 66];
            tr[fc * 4 + 0] = f2b(v[0]); tr[fc * 4 + 1] = f2b(v[1]);
            tr[fc * 4 + 2] = f2b(v[2]); tr[fc * 4 + 3] = f2b(v[3]);
        }
        __syncthreads();
#pragma unroll
        for (int it = 0; it < 4; it++) {
            int sid = it * 256 + tid;
            int cr = sid >> 4, cc = sid & 15;
            us4 v = (us4){ tile[(cc * 4 + 0) * 66 + cr], tile[(cc * 4 + 1) * 66 + cr],
                           tile[(cc * 4 + 2) * 66 + cr], tile[(cc * 4 + 3) * 66 + cr] };
            *(us4*)&dst[(size_t)(c0 + cr) * ldst_ + r0 + cc * 4] = v;
        }
    } else if (i < 2048) {
        int j = i - 768;
        int pp = j >> 2, d0 = (j & 3) * 64;
#pragma unroll
        for (int it = 0; it < 6; it++) {
            int fid = it * 256 + tid;
            int fr = fid / 24, fc = fid % 24;
            f32x4 v = *(const f32x4*)&Wh[((size_t)(d0 + fr) * 320 + pp) * 96 + fc * 4];
            ushort* tr = &tile[fr * 98];
            tr[fc * 4 + 0] = f2b(v[0]); tr[fc * 4 + 1] = f2b(v[1]);
            tr[fc * 4 + 2] = f2b(v[2]); tr[fc * 4 + 3] = f2b(v[3]);
        }
        __syncthreads();
#pragma unroll
        for (int it = 0; it < 6; it++) {
            int sid = it * 256 + tid;
            int tr = sid >> 4, dc = sid & 15;
            us4 v = (us4){ tile[(dc * 4 + 0) * 98 + tr], tile[(dc * 4 + 1) * 98 + tr],
                           tile[(dc * 4 + 2) * 98 + tr], tile[(dc * 4 + 3) * 98 + tr] };
            *(us4*)&WhT2[(size_t)tr * KHEAD + pp * 256 + d0 + dc * 4] = v;
        }
    } else {
        int j = i - 2048;
        int bc = j / 80, pb = j % 80;
        int wave = tid >> 6, lane = tid & 63;
        f32x4 zv = *(const f32x4*)&z[bc * CTX + tid * 4];
        float s1 = zv[0] + zv[1] + zv[2] + zv[3];
        float s2 = zv[0] * zv[0] + zv[1] * zv[1] + zv[2] * zv[2] + zv[3] * zv[3];
#pragma unroll
        for (int off = 1; off < 64; off <<= 1) {
            s1 += __shfl_xor(s1, off);
            s2 += __shfl_xor(s2, off);
        }
        if (lane == 0) { red1[wave] = s1; red2[wave] = s2; }
        __syncthreads();
        s1 = red1[0] + red1[1] + red1[2] + red1[3];
        s2 = red2[0] + red2[1] + red2[2] + red2[3];
        float m = s1 * (1.0f / CTX);
        float var = s2 * (1.0f / CTX) - m * m;
        float sd = sqrtf(var + EPS);
        int c = bc & 7;
        float w = rw[c], bb = rb[c];
        float inv_sd_w = w / sd;
#pragma unroll
        for (int k = 0; k < 4; k++) szn[tid * 4 + k] = (zv[k] - m) * inv_sd_w + bb;
        if (pb == 0) {
            if (tid < TGT) outp[bc * TGT + tid] = (bhv[tid] - bb) / (w + EPS * EPS) * sd + m;
            if (tid == 0) scalef[bc] = sd / (w + EPS * EPS);
        }
        __syncthreads();
#pragma unroll
        for (int pi = 0; pi < 4; pi++) {
            int p = pb * 4 + pi, d = tid;
            float acc;
            if (p < NF) {
                acc = bfv[d];
                int base = p * 4;
#pragma unroll
                for (int q = 0; q < 8; q++)
                    acc += szn[min(base + q, CTX - 1)] * Wf[q * DM + d];
            } else {
                acc = bcv[d];
                int base = (p - NF) * 16;
#pragma unroll
                for (int q = 0; q < 32; q++)
                    acc += szn[min(base + q, CTX - 1)] * Wc[q * DM + d];
            }
            acc += Wpos[p * DM + d];
            u[((size_t)bc * TOTAL + p) * DM + d] = f2b(acc);
        }
    }
}

// ---------------- bf16 MFMA GEMM, 64x64 tile, 2-phase double-buffered ----------------
// QKV=1: Q -> linear per-head plane; K -> perm_k attention-LDS-image; V -> perm_v image.
template <int GELU, int QKV>
__global__ __launch_bounds__(256) void k_gemm_mfma(const ushort* __restrict__ A,
                                                   const ushort* __restrict__ Wt,
                                                   const float* __restrict__ b0,
                                                   const float* __restrict__ b1,
                                                   const float* __restrict__ b2,
                                                   ushort* __restrict__ C,
                                                   ushort* __restrict__ C2,
                                                   int Mm, int N, int K) {
    __shared__ ushort As[2][64][32];
    __shared__ ushort Bs[2][64][32];
    int tid = threadIdx.x;
    int wave = tid >> 6, lane = tid & 63;
    int quad = lane >> 4, l16 = lane & 15;
    int m0 = blockIdx.y * 64, n0 = blockIdx.x * 64;

    f32x4 acc[4];
#pragma unroll
    for (int nt = 0; nt < 4; nt++) acc[nt] = (f32x4){0.f, 0.f, 0.f, 0.f};

    int srow = wave * 16 + (lane >> 2);
    int sc = (lane & 3) ^ ((srow >> 1) & 3);
    const ushort* Ag = &A[(size_t)(m0 + srow) * K + sc * 8];
    const ushort* Bg = &Wt[(size_t)(n0 + srow) * K + sc * 8];
    int rchunk = (quad ^ ((l16 >> 1) & 3)) * 8;

    ldst16(Ag, &As[0][wave * 16][0]);
    ldst16(Bg, &Bs[0][wave * 16][0]);
    PIPE_BARRIER();

    int nstep = K >> 5;
    int cur = 0;
    for (int t = 0; t < nstep; t++) {
        if (t + 1 < nstep) {
            ldst16(Ag + (t + 1) * 32, &As[cur ^ 1][wave * 16][0]);
            ldst16(Bg + (t + 1) * 32, &Bs[cur ^ 1][wave * 16][0]);
        }
        short8 af = *(const short8*)&As[cur][wave * 16 + l16][rchunk];
#pragma unroll
        for (int nt = 0; nt < 4; nt++) {
            short8 bf = *(const short8*)&Bs[cur][nt * 16 + l16][rchunk];
            acc[nt] = __builtin_amdgcn_mfma_f32_16x16x32_bf16(af, bf, acc[nt], 0, 0, 0);
        }
        PIPE_BARRIER();
        cur ^= 1;
    }
#pragma unroll
    for (int nt = 0; nt < 4; nt++) {
        int col = n0 + nt * 16 + l16;
        float bi;
        if (QKV) {
            int bs = (n0 + nt * 16) >> 8;
            const float* bp = bs == 0 ? b0 : (bs == 1 ? b1 : b2);
            bi = bp[col & 255];
        } else {
            bi = b0[col];
        }
#pragma unroll
        for (int r = 0; r < 4; r++) {
            int rowm = m0 + wave * 16 + quad * 4 + r;
            float vv = acc[nt][r] + bi;
            if (GELU) vv = vv * 0.5f * (1.0f + erff(vv * 0.70710678118f));
            if (QKV) {
                int bs = col >> 8;
                int c = col & 255, hh = c >> 4, d = c & 15;
                int bb = rowm / 320, j = rowm - bb * 320;
                size_t plane = (size_t)hh * (M * DK) + (size_t)bb * (TOTAL * DK);
                if (bs == 0) {
                    C[plane + (size_t)j * DK + d] = f2b(vv);
                } else if (bs == 1) {
                    int off = (((j >> 4) * 2 + (d >> 3)) * 16 + (j & 15)) * 8 + (d & 7);
                    C[(size_t)M * DM + plane + off] = f2b(vv);
                } else {
                    int off = ((j >> 5) * 4 + ((j & 15) >> 2)) * 128 +
                              (((j >> 4) & 1) << 2) + (j & 3) + d * 8;
                    C2[plane + off] = f2b(vv);
                }
            } else {
                C[(size_t)rowm * N + col] = f2b(vv);
            }
        }
    }
}

// ---------------- fused post-attention block: O-proj+LN1 (LDS) + FFN1+GELU + FFN2+LN2 ----------------
// 16 rows/block. All B operands staged via ldst16 (ln16 pattern). LN1 output lives only in LDS.
__global__ __launch_bounds__(256) void k_block(const ushort* __restrict__ ax,
                                               const ushort* __restrict__ WtO,
                                               const float* __restrict__ bO,
                                               const float* __restrict__ ln1s,
                                               const float* __restrict__ ln1b,
                                               const ushort* __restrict__ F1t,  // [1024][256]
                                               const ushort* __restrict__ F2t,  // [256][1024]
                                               const float* __restrict__ c1v,
                                               const float* __restrict__ c2v,
                                               const float* __restrict__ ln2s,
                                               const float* __restrict__ ln2b,
                                               ushort* __restrict__ u) {
    __shared__ ushort As[2][16][32];
    __shared__ ushort Bs[2][256][32];
    __shared__ __align__(16) ushort Au[16][264];   // LN1 output (swizzled)
    __shared__ __align__(16) ushort Hs[16][264];   // gelu(h) chunk (swizzled)
    __shared__ float ps1[16][4], ps2[16][4];
    int tid = threadIdx.x;
    int wave = tid >> 6, lane = tid & 63;
    int quad = lane >> 4, l16 = lane & 15;
    int m0 = blockIdx.x * 16;

    int brow = wave * 16 + (lane >> 2);
    int bsw = (lane & 3) ^ ((brow >> 1) & 3);
    int ar = lane >> 2;
    int ac = (lane & 3) ^ ((ar >> 1) & 3);
    int rchunk = (quad ^ ((l16 >> 1) & 3)) * 8;

    // ================= phase 0: O-proj (K=256) + bias + residual + LN1 -> Au =================
    {
        f32x4 acc[4];
#pragma unroll
        for (int nt = 0; nt < 4; nt++) acc[nt] = (f32x4){0.f, 0.f, 0.f, 0.f};
        const ushort* Ag = &ax[(size_t)(m0 + ar) * 256 + ac * 8];
        const ushort* Bg = &WtO[(size_t)brow * 256 + bsw * 8];

        if (tid < 64) ldst16(Ag, &As[0][0][0]);
#pragma unroll
        for (int i = 0; i < 4; i++) ldst16(Bg + (size_t)i * 64 * 256, &Bs[0][i * 64 + wave * 16][0]);
        PIPE_BARRIER();
        int cur = 0;
        for (int t = 0; t < 8; t++) {
            if (t + 1 < 8) {
                if (tid < 64) ldst16(Ag + (t + 1) * 32, &As[cur ^ 1][0][0]);
#pragma unroll
                for (int i = 0; i < 4; i++)
                    ldst16(Bg + (size_t)i * 64 * 256 + (t + 1) * 32, &Bs[cur ^ 1][i * 64 + wave * 16][0]);
            }
            short8 af = *(const short8*)&As[cur][l16][rchunk];
#pragma unroll
            for (int nt = 0; nt < 4; nt++) {
                short8 bf = *(const short8*)&Bs[cur][wave * 64 + nt * 16 + l16][rchunk];
                acc[nt] = __builtin_amdgcn_mfma_f32_16x16x32_bf16(af, bf, acc[nt], 0, 0, 0);
            }
            PIPE_BARRIER();
            cur ^= 1;
        }
        float xv[4][4];
#pragma unroll
        for (int r = 0; r < 4; r++) {
            int rowg = m0 + quad * 4 + r;
            float s1 = 0.f, s2 = 0.f;
#pragma unroll
            for (int nt = 0; nt < 4; nt++) {
                int col = wave * 64 + nt * 16 + l16;
                float x = acc[nt][r] + bO[col] + bu2f(u[(size_t)rowg * DM + col]);
                xv[r][nt] = x; s1 += x; s2 += x * x;
            }
            s1 += __shfl_xor(s1, 1); s2 += __shfl_xor(s2, 1);
            s1 += __shfl_xor(s1, 2); s2 += __shfl_xor(s2, 2);
            s1 += __shfl_xor(s1, 4); s2 += __shfl_xor(s2, 4);
            s1 += __shfl_xor(s1, 8); s2 += __shfl_xor(s2, 8);
            if (l16 == 0) { ps1[quad * 4 + r][wave] = s1; ps2[quad * 4 + r][wave] = s2; }
        }
        __syncthreads();
#pragma unroll
        for (int r = 0; r < 4; r++) {
            int rowl = quad * 4 + r;
            float s1 = ps1[rowl][0] + ps1[rowl][1] + ps1[rowl][2] + ps1[rowl][3];
            float s2 = ps2[rowl][0] + ps2[rowl][1] + ps2[rowl][2] + ps2[rowl][3];
            float m = s1 * (1.0f / DM);
            float var = s2 * (1.0f / DM) - m * m;
            float rs = rsqrtf(var + EPS);
#pragma unroll
            for (int nt = 0; nt < 4; nt++) {
                int col = wave * 64 + nt * 16 + l16;
                int k32 = col >> 5, pp = (col >> 3) & 3, e = col & 7;
                int pphys = pp ^ ((rowl >> 1) & 3);
                Au[rowl][k32 * 32 + pphys * 8 + e] =
                    f2b((xv[r][nt] - m) * rs * ln1s[col] + ln1b[col]);
            }
        }
        __syncthreads();
    }

    // ================= FFN: 4 chunks of 256 h-cols; FFN2 accumulates across chunks =================
    f32x4 acc2[4];
#pragma unroll
    for (int nt = 0; nt < 4; nt++) acc2[nt] = (f32x4){0.f, 0.f, 0.f, 0.f};

    for (int c = 0; c < 4; c++) {
        // ---- FFN1 chunk c: h[:, c*256..+255] = Au @ F1t-rows, K=256 ----
        f32x4 acc1[4];
#pragma unroll
        for (int nt = 0; nt < 4; nt++) acc1[nt] = (f32x4){0.f, 0.f, 0.f, 0.f};
        const ushort* Bg1 = &F1t[(size_t)(c * 256 + brow) * 256 + bsw * 8];
#pragma unroll
        for (int i = 0; i < 4; i++) ldst16(Bg1 + (size_t)i * 64 * 256, &Bs[0][i * 64 + wave * 16][0]);
        PIPE_BARRIER();
        int cur = 0;
        for (int t = 0; t < 8; t++) {
            if (t + 1 < 8) {
#pragma unroll
                for (int i = 0; i < 4; i++)
                    ldst16(Bg1 + (size_t)i * 64 * 256 + (t + 1) * 32, &Bs[cur ^ 1][i * 64 + wave * 16][0]);
            }
            short8 af = *(const short8*)&Au[l16][t * 32 + rchunk];
#pragma unroll
            for (int nt = 0; nt < 4; nt++) {
                short8 bf = *(const short8*)&Bs[cur][wave * 64 + nt * 16 + l16][rchunk];
                acc1[nt] = __builtin_amdgcn_mfma_f32_16x16x32_bf16(af, bf, acc1[nt], 0, 0, 0);
            }
            PIPE_BARRIER();
            cur ^= 1;
        }
        // gelu -> Hs (chunk-local cols 0..255)
#pragma unroll
        for (int nt = 0; nt < 4; nt++) {
            int cc = wave * 64 + nt * 16 + l16;
            float bi = c1v[c * 256 + cc];
            int k32 = cc >> 5, pp = (cc >> 3) & 3, e = cc & 7;
#pragma unroll
            for (int r = 0; r < 4; r++) {
                int row = quad * 4 + r;
                float vv = acc1[nt][r] + bi;
                vv = vv * 0.5f * (1.0f + erff(vv * 0.70710678118f));
                int pphys = pp ^ ((row >> 1) & 3);
                Hs[row][k32 * 32 + pphys * 8 + e] = f2b(vv);
            }
        }
        __syncthreads();
        // ---- FFN2 partial: acc2 += Hs @ F2t[:, c*256..+255] ----
        const ushort* Bg2 = &F2t[(size_t)brow * 1024 + c * 256 + bsw * 8];
#pragma unroll
        for (int i = 0; i < 4; i++) ldst16(Bg2 + (size_t)i * 64 * 1024, &Bs[0][i * 64 + wave * 16][0]);
        PIPE_BARRIER();
        cur = 0;
        for (int t = 0; t < 8; t++) {
            if (t + 1 < 8) {
#pragma unroll
                for (int i = 0; i < 4; i++)
                    ldst16(Bg2 + (size_t)i * 64 * 1024 + (t + 1) * 32, &Bs[cur ^ 1][i * 64 + wave * 16][0]);
            }
            short8 af = *(const short8*)&Hs[l16][t * 32 + rchunk];
#pragma unroll
            for (int nt = 0; nt < 4; nt++) {
                short8 bf = *(const short8*)&Bs[cur][wave * 64 + nt * 16 + l16][rchunk];
                acc2[nt] = __builtin_amdgcn_mfma_f32_16x16x32_bf16(af, bf, acc2[nt], 0, 0, 0);
            }
            PIPE_BARRIER();
            cur ^= 1;
        }
    }

    // ================= epilogue: bias + residual(Au) + LN2 -> global u =================
    float xv[4][4];
#pragma unroll
    for (int r = 0; r < 4; r++) {
        int rowl = quad * 4 + r;
        float s1 = 0.f, s2 = 0.f;
#pragma unroll
        for (int nt = 0; nt < 4; nt++) {
            int col = wave * 64 + nt * 16 + l16;
            int k32 = col >> 5, pp = (col >> 3) & 3, e = col & 7;
            int pphys = pp ^ ((rowl >> 1) & 3);
            float x = acc2[nt][r] + c2v[col] + bu2f(Au[rowl][k32 * 32 + pphys * 8 + e]);
            xv[r][nt] = x; s1 += x; s2 += x * x;
        }
        s1 += __shfl_xor(s1, 1); s2 += __shfl_xor(s2, 1);
        s1 += __shfl_xor(s1, 2); s2 += __shfl_xor(s2, 2);
        s1 += __shfl_xor(s1, 4); s2 += __shfl_xor(s2, 4);
        s1 += __shfl_xor(s1, 8); s2 += __shfl_xor(s2, 8);
        if (l16 == 0) { ps1[rowl][wave] = s1; ps2[rowl][wave] = s2; }
    }
    __syncthreads();
#pragma unroll
    for (int r = 0; r < 4; r++) {
        int rowl = quad * 4 + r, rowg = m0 + rowl;
        float s1 = ps1[rowl][0] + ps1[rowl][1] + ps1[rowl][2] + ps1[rowl][3];
        float s2 = ps2[rowl][0] + ps2[rowl][1] + ps2[rowl][2] + ps2[rowl][3];
        float m = s1 * (1.0f / DM);
        float var = s2 * (1.0f / DM) - m * m;
        float rs = rsqrtf(var + EPS);
#pragma unroll
        for (int nt = 0; nt < 4; nt++) {
            int col = wave * 64 + nt * 16 + l16;
            u[(size_t)rowg * DM + col] = f2b((xv[r][nt] - m) * rs * ln2s[col] + ln2b[col]);
        }
    }
}

// ---------------- attention v8: all-DMA staging (pre-permuted K/V), ONE barrier ----------------
__global__ __launch_bounds__(256, 3) void k_attn(const ushort* __restrict__ qk, const ushort* __restrict__ vm,
                                                 ushort* __restrict__ ao, int nj) {
    __shared__ __align__(16) ushort sh[25600];
    int bh = blockIdx.x, b = bh >> 4, h = bh & 15;
    int i0 = blockIdx.y * 64;
    int t = threadIdx.x, wave = t >> 6, lane = t & 63, quad = lane >> 4, l16 = lane & 15;
    const short8 zero8 = (short8){0, 0, 0, 0, 0, 0, 0, 0};
    size_t hplane = (size_t)h * (M * DK) + (size_t)b * (TOTAL * DK);

    int nchunks = (nj + 1) * 10;
    for (int c = wave; c < nchunks; c += 4) {
        int s = c / 10, cc = c - s * 10;
        const ushort* src = (s < nj)
            ? qk + (size_t)(2 * s + 1) * (M * DM) + hplane + cc * 512
            : vm + hplane + cc * 512;
        int dstbase = (s < nj ? s * 5120 : 20480) + cc * 512;
        ldst16(src + lane * 8, &sh[dstbase]);
    }
    short8 qfr[4] = { zero8, zero8, zero8, zero8 };
    int qrow = i0 + wave * 16 + l16;
#pragma unroll
    for (int jl = 0; jl < 4; jl++)
        if (jl < nj && quad < 2)
            qfr[jl] = *(const short8*)&qk[(size_t)(2 * jl) * (M * DM) + hplane +
                                          (size_t)qrow * DK + quad * 8];
    PIPE_BARRIER();

    f32x4 acc[20];
#pragma unroll
    for (int nt = 0; nt < 20; nt++) acc[nt] = (f32x4){0.f, 0.f, 0.f, 0.f};

    __builtin_amdgcn_s_setprio(1);
#pragma unroll
    for (int jl = 0; jl < 4; jl++) {
        if (jl < nj) {
            int kb = jl * 5120;
#pragma unroll
            for (int nt = 0; nt < 20; nt++) {
                short8 kf = *(const short8*)&sh[kb + ((nt * 2 + (quad & 1)) * 16 + l16) * 8];
                acc[nt] = __builtin_amdgcn_mfma_f32_16x16x32_bf16(kf, qfr[jl], acc[nt], 0, 0, 0);
            }
        }
    }
    __builtin_amdgcn_s_setprio(0);

    float mx = -1e30f;
#pragma unroll
    for (int nt = 0; nt < 20; nt++)
#pragma unroll
        for (int r = 0; r < 4; r++) { acc[nt][r] *= SCALE; mx = fmaxf(mx, acc[nt][r]); }
    mx = fmaxf(mx, __shfl_xor(mx, 16));
    mx = fmaxf(mx, __shfl_xor(mx, 32));
    float sum = 0.f;
#pragma unroll
    for (int nt = 0; nt < 20; nt++)
#pragma unroll
        for (int r = 0; r < 4; r++) { acc[nt][r] = __expf(acc[nt][r] - mx); sum += acc[nt][r]; }
    sum += __shfl_xor(sum, 16);
    sum += __shfl_xor(sum, 32);
    float inv = 1.f / sum;
#pragma unroll
    for (int nt = 0; nt < 20; nt++)
#pragma unroll
        for (int r = 0; r < 4; r++) acc[nt][r] *= inv;

    f32x4 oacc = (f32x4){0.f, 0.f, 0.f, 0.f};
    __builtin_amdgcn_s_setprio(1);
#pragma unroll
    for (int jt2 = 0; jt2 < 10; jt2++) {
        short8 vt = *(const short8*)&sh[20480 + ((jt2 * 4 + quad) * 16 + l16) * 8];
        union { short8 v; uint u[4]; } pf;
        pf.u[0] = pack2(acc[2 * jt2][0], acc[2 * jt2][1]);
        pf.u[1] = pack2(acc[2 * jt2][2], acc[2 * jt2][3]);
        pf.u[2] = pack2(acc[2 * jt2 + 1][0], acc[2 * jt2 + 1][1]);
        pf.u[3] = pack2(acc[2 * jt2 + 1][2], acc[2 * jt2 + 1][3]);
        oacc = __builtin_amdgcn_mfma_f32_16x16x32_bf16(vt, pf.v, oacc, 0, 0, 0);
    }
    __builtin_amdgcn_s_setprio(0);
    us4 ov4 = (us4){f2b(oacc[0]), f2b(oacc[1]), f2b(oacc[2]), f2b(oacc[3])};
    *(us4*)&ao[((size_t)b * TOTAL + i0 + wave * 16 + l16) * DM + h * DK + quad * 4] = ov4;
}

// ---------------- head GEMM: MFMA split-K, atomic accumulate into pre-initialized out ----------------
__global__ __launch_bounds__(256) void k_head(const ushort* __restrict__ u, const ushort* __restrict__ WhT2,
                                              const float* __restrict__ scalef, float* __restrict__ out) {
    int t0 = blockIdx.x * 16;
    int wave = threadIdx.x >> 6, lane = threadIdx.x & 63;
    int quad = lane >> 4, l16 = lane & 15;
    int chunk = blockIdx.y * 4 + wave;
    int kbeg = chunk * 1024;
    f32x4 acc = (f32x4){0.f, 0.f, 0.f, 0.f};
    const ushort* za = &u[(size_t)l16 * KHEAD + quad * 8];
    const ushort* wb = &WhT2[(size_t)(t0 + l16) * KHEAD + quad * 8];
#pragma unroll 4
    for (int k = kbeg; k < kbeg + 1024; k += 32) {
        short8 af = *(const short8*)&za[k];
        short8 bf = *(const short8*)&wb[k];
        acc = __builtin_amdgcn_mfma_f32_16x16x32_bf16(af, bf, acc, 0, 0, 0);
    }
#pragma unroll
    for (int r = 0; r < 4; r++) {
        int bcr = quad * 4 + r;
        atomicAdd(&out[bcr * TGT + t0 + l16], acc[r] * scalef[bcr]);
    }
}

extern "C" void kernel_launch(void* const* d_in, const int* in_sizes, int n_in,
                              void* d_out, int out_size, void* d_ws, size_t ws_size,
                              hipStream_t stream) {
    const float* z       = (const float*)d_in[0];
    const float* revin_w = (const float*)d_in[1];
    const float* revin_b = (const float*)d_in[2];
    const float* Wf      = (const float*)d_in[3];
    const float* bfv     = (const float*)d_in[4];
    const float* Wc      = (const float*)d_in[5];
    const float* bcv     = (const float*)d_in[6];
    const float* Wpos    = (const float*)d_in[7];
    const float* WQ      = (const float*)d_in[8];
    const float* bQ      = (const float*)d_in[9];
    const float* WK      = (const float*)d_in[10];
    const float* bK      = (const float*)d_in[11];
    const float* WV      = (const float*)d_in[12];
    const float* bV      = (const float*)d_in[13];
    const float* WO      = (const float*)d_in[14];
    const float* bO      = (const float*)d_in[15];
    const float* ln1s    = (const float*)d_in[16];
    const float* ln1b    = (const float*)d_in[17];
    const float* ln2s    = (const float*)d_in[18];
    const float* ln2b    = (const float*)d_in[19];
    const float* F1      = (const float*)d_in[20];
    const float* c1      = (const float*)d_in[21];
    const float* F2      = (const float*)d_in[22];
    const float* c2      = (const float*)d_in[23];
    const float* Wh      = (const float*)d_in[24];
    const float* bh      = (const float*)d_in[25];
    float* out = (float*)d_out;

    char* p = (char*)d_ws;
    float* scalef = (float*)p;   p += 16 * 4;
    p = (char*)(((size_t)p + 255) & ~255ull);
    ushort* u     = (ushort*)p;  p += (size_t)M * DM * 2;
    ushort* qkbuf = (ushort*)p;  p += (size_t)NL * 2 * M * DM * 2;   // per-layer [Q,K] head planes
    ushort* vbuf  = (ushort*)p;  p += (size_t)M * DM * 2;            // V head planes (permuted)
    ushort* ax    = (ushort*)p;  p += (size_t)M * DM * 2;
    ushort* Wtqkv = (ushort*)p;  p += (size_t)NL * 768 * 256 * 2;
    ushort* WtO   = (ushort*)p;  p += (size_t)NL * 256 * 256 * 2;
    ushort* Ft1   = (ushort*)p;  p += (size_t)NL * 1024 * 256 * 2;
    ushort* Ft2   = (ushort*)p;  p += (size_t)NL * 256 * 1024 * 2;
    ushort* WhT2  = (ushort*)p;  p += (size_t)TGT * KHEAD * 2;

    k_prep<<<3328, 256, 0, stream>>>(WQ, WK, WV, WO, F1, F2, Wh,
                                     Wtqkv, WtO, Ft1, Ft2, WhT2,
                                     z, revin_w, revin_b,
                                     Wf, bfv, Wc, bcv, Wpos, u,
                                     bh, out, scalef);

    for (int l = 0; l < NL; l++) {
        k_gemm_mfma<0, 1><<<dim3(12, 80), 256, 0, stream>>>(
            u, Wtqkv + (size_t)l * 768 * 256, bQ + l * DM, bK + l * DM, bV + l * DM,
            qkbuf + (size_t)l * 2 * M * DM, vbuf, M, 768, 256);
        k_attn<<<dim3(NB * NH, 5), 256, 0, stream>>>(qkbuf, vbuf, ax, l + 1);
        k_block<<<M / 16, 256, 0, stream>>>(
            ax, WtO + (size_t)l * 65536, bO + l * DM, ln1s + l * DM, ln1b + l * DM,
            Ft1 + (size_t)l * 262144, Ft2 + (size_t)l * 262144,
            c1 + l * DFF, c2 + l * DM, ln2s + l * DM, ln2b + l * DM, u);
    }

    k_head<<<dim3(TGT / 16, 20), 256, 0, stream>>>(u, WhT2, scalef, out);
}

// Round 12
// 409.648 us; speedup vs baseline: 1.3249x; 1.0234x over previous
//
#include <hip/hip_runtime.h>
#include <math.h>

typedef unsigned short ushort;
typedef unsigned int uint;
typedef __attribute__((ext_vector_type(8))) short short8;
typedef __attribute__((ext_vector_type(4))) float f32x4;
typedef __attribute__((ext_vector_type(4))) ushort us4;

constexpr int BS = 2, C_IN = 8, CTX = 1024, TGT = 96;
constexpr int DM = 256, NH = 16, DFF = 1024, NL = 4;
constexpr int NF = 256, TOTAL = 320;
constexpr int NB = 16;
constexpr int DK = 16;
constexpr float EPS = 1e-5f;
constexpr float SCALE = 0.25f;
constexpr int KHEAD = DM * TOTAL;  // 81920
constexpr int M = NB * TOTAL;      // 5120

__device__ __forceinline__ ushort f2b(float x) {
    uint u = __float_as_uint(x);
    u += 0x7fff + ((u >> 16) & 1);
    return (ushort)(u >> 16);
}
__device__ __forceinline__ float bu2f(ushort x) { return __uint_as_float(((uint)x) << 16); }
__device__ __forceinline__ uint pack2(float a, float b) { return (uint)f2b(a) | ((uint)f2b(b) << 16); }

typedef __attribute__((address_space(3))) uint lds_u32;
typedef const __attribute__((address_space(1))) uint glb_u32;
__device__ __forceinline__ void ldst16(const void* g, void* l) {
    __builtin_amdgcn_global_load_lds((glb_u32*)g, (lds_u32*)l, 16, 0, 0);
}

#define PIPE_BARRIER() asm volatile("s_waitcnt vmcnt(0)\n\ts_barrier" ::: "memory")

// ---------------- prep v2: vectorized weight transposes + RevIN + embed + out-init ----------------
__global__ __launch_bounds__(256) void k_prep(
        const float* __restrict__ WQ, const float* __restrict__ WK,
        const float* __restrict__ WV, const float* __restrict__ WO,
        const float* __restrict__ F1, const float* __restrict__ F2,
        const float* __restrict__ Wh,
        ushort* __restrict__ Wtqkv, ushort* __restrict__ WtO,
        ushort* __restrict__ Ft1, ushort* __restrict__ Ft2,
        ushort* __restrict__ WhT2,
        const float* __restrict__ z, const float* __restrict__ rw,
        const float* __restrict__ rb,
        const float* __restrict__ Wf, const float* __restrict__ bfv,
        const float* __restrict__ Wc, const float* __restrict__ bcv,
        const float* __restrict__ Wpos, ushort* __restrict__ u,
        const float* __restrict__ bhv, float* __restrict__ outp,
        float* __restrict__ scalef) {
    __shared__ __align__(16) ushort tile[64 * 98];
    __shared__ float szn[CTX];
    __shared__ float red1[4], red2[4];
    int i = blockIdx.x, tid = threadIdx.x;

    if (i < 768) {
        const float* src; ushort* dst; int lsrc, ldst_, r0, c0;
        if (i < 256) {
            int mat = i >> 4, l = mat >> 2, w = mat & 3;
            src = (w == 0 ? WQ : (w == 1 ? WK : (w == 2 ? WV : WO))) + l * 65536;
            dst = (w < 3) ? (Wtqkv + (size_t)l * 768 * 256 + w * 65536)
                          : (WtO + (size_t)l * 65536);
            lsrc = 256; ldst_ = 256; r0 = ((i >> 2) & 3) * 64; c0 = (i & 3) * 64;
        } else if (i < 512) {
            int j = i - 256, l = j >> 6, t = j & 63;
            src = F1 + (size_t)l * 262144; dst = Ft1 + (size_t)l * 262144;
            lsrc = 1024; ldst_ = 256; r0 = (t >> 4) * 64; c0 = (t & 15) * 64;
        } else {
            int j = i - 512, l = j >> 6, t = j & 63;
            src = F2 + (size_t)l * 262144; dst = Ft2 + (size_t)l * 262144;
            lsrc = 256; ldst_ = 1024; r0 = (t >> 2) * 64; c0 = (t & 3) * 64;
        }
#pragma unroll
        for (int it = 0; it < 4; it++) {
            int fid = it * 256 + tid;
            int fr = fid >> 4, fc = fid & 15;
            f32x4 v = *(const f32x4*)&src[(size_t)(r0 + fr) * lsrc + c0 + fc * 4];
            ushort* tr = &tile[fr * 66];
            tr[fc * 4 + 0] = f2b(v[0]); tr[fc * 4 + 1] = f2b(v[1]);
            tr[fc * 4 + 2] = f2b(v[2]); tr[fc * 4 + 3] = f2b(v[3]);
        }
        __syncthreads();
#pragma unroll
        for (int it = 0; it < 4; it++) {
            int sid = it * 256 + tid;
            int cr = sid >> 4, cc = sid & 15;
            us4 v = (us4){ tile[(cc * 4 + 0) * 66 + cr], tile[(cc * 4 + 1) * 66 + cr],
                           tile[(cc * 4 + 2) * 66 + cr], tile[(cc * 4 + 3) * 66 + cr] };
            *(us4*)&dst[(size_t)(c0 + cr) * ldst_ + r0 + cc * 4] = v;
        }
    } else if (i < 2048) {
        int j = i - 768;
        int pp = j >> 2, d0 = (j & 3) * 64;
#pragma unroll
        for (int it = 0; it < 6; it++) {
            int fid = it * 256 + tid;
            int fr = fid / 24, fc = fid % 24;
            f32x4 v = *(const f32x4*)&Wh[((size_t)(d0 + fr) * 320 + pp) * 96 + fc * 4];
            ushort* tr = &tile[fr * 98];
            tr[fc * 4 + 0] = f2b(v[0]); tr[fc * 4 + 1] = f2b(v[1]);
            tr[fc * 4 + 2] = f2b(v[2]); tr[fc * 4 + 3] = f2b(v[3]);
        }
        __syncthreads();
#pragma unroll
        for (int it = 0; it < 6; it++) {
            int sid = it * 256 + tid;
            int tr = sid >> 4, dc = sid & 15;
            us4 v = (us4){ tile[(dc * 4 + 0) * 98 + tr], tile[(dc * 4 + 1) * 98 + tr],
                           tile[(dc * 4 + 2) * 98 + tr], tile[(dc * 4 + 3) * 98 + tr] };
            *(us4*)&WhT2[(size_t)tr * KHEAD + pp * 256 + d0 + dc * 4] = v;
        }
    } else {
        int j = i - 2048;
        int bc = j / 80, pb = j % 80;
        int wave = tid >> 6, lane = tid & 63;
        f32x4 zv = *(const f32x4*)&z[bc * CTX + tid * 4];
        float s1 = zv[0] + zv[1] + zv[2] + zv[3];
        float s2 = zv[0] * zv[0] + zv[1] * zv[1] + zv[2] * zv[2] + zv[3] * zv[3];
#pragma unroll
        for (int off = 1; off < 64; off <<= 1) {
            s1 += __shfl_xor(s1, off);
            s2 += __shfl_xor(s2, off);
        }
        if (lane == 0) { red1[wave] = s1; red2[wave] = s2; }
        __syncthreads();
        s1 = red1[0] + red1[1] + red1[2] + red1[3];
        s2 = red2[0] + red2[1] + red2[2] + red2[3];
        float m = s1 * (1.0f / CTX);
        float var = s2 * (1.0f / CTX) - m * m;
        float sd = sqrtf(var + EPS);
        int c = bc & 7;
        float w = rw[c], bb = rb[c];
        float inv_sd_w = w / sd;
#pragma unroll
        for (int k = 0; k < 4; k++) szn[tid * 4 + k] = (zv[k] - m) * inv_sd_w + bb;
        if (pb == 0) {
            if (tid < TGT) outp[bc * TGT + tid] = (bhv[tid] - bb) / (w + EPS * EPS) * sd + m;
            if (tid == 0) scalef[bc] = sd / (w + EPS * EPS);
        }
        __syncthreads();
#pragma unroll
        for (int pi = 0; pi < 4; pi++) {
            int p = pb * 4 + pi, d = tid;
            float acc;
            if (p < NF) {
                acc = bfv[d];
                int base = p * 4;
#pragma unroll
                for (int q = 0; q < 8; q++)
                    acc += szn[min(base + q, CTX - 1)] * Wf[q * DM + d];
            } else {
                acc = bcv[d];
                int base = (p - NF) * 16;
#pragma unroll
                for (int q = 0; q < 32; q++)
                    acc += szn[min(base + q, CTX - 1)] * Wc[q * DM + d];
            }
            acc += Wpos[p * DM + d];
            u[((size_t)bc * TOTAL + p) * DM + d] = f2b(acc);
        }
    }
}

// ---------------- bf16 MFMA GEMM, 64x64 tile, 2-phase double-buffered ----------------
// QKV=1: Q -> linear per-head plane; K -> perm_k attention-LDS-image; V -> perm_v image.
template <int GELU, int QKV>
__global__ __launch_bounds__(256) void k_gemm_mfma(const ushort* __restrict__ A,
                                                   const ushort* __restrict__ Wt,
                                                   const float* __restrict__ b0,
                                                   const float* __restrict__ b1,
                                                   const float* __restrict__ b2,
                                                   ushort* __restrict__ C,
                                                   ushort* __restrict__ C2,
                                                   int Mm, int N, int K) {
    __shared__ ushort As[2][64][32];
    __shared__ ushort Bs[2][64][32];
    int tid = threadIdx.x;
    int wave = tid >> 6, lane = tid & 63;
    int quad = lane >> 4, l16 = lane & 15;
    int m0 = blockIdx.y * 64, n0 = blockIdx.x * 64;

    f32x4 acc[4];
#pragma unroll
    for (int nt = 0; nt < 4; nt++) acc[nt] = (f32x4){0.f, 0.f, 0.f, 0.f};

    int srow = wave * 16 + (lane >> 2);
    int sc = (lane & 3) ^ ((srow >> 1) & 3);
    const ushort* Ag = &A[(size_t)(m0 + srow) * K + sc * 8];
    const ushort* Bg = &Wt[(size_t)(n0 + srow) * K + sc * 8];
    int rchunk = (quad ^ ((l16 >> 1) & 3)) * 8;

    ldst16(Ag, &As[0][wave * 16][0]);
    ldst16(Bg, &Bs[0][wave * 16][0]);
    PIPE_BARRIER();

    int nstep = K >> 5;
    int cur = 0;
    for (int t = 0; t < nstep; t++) {
        if (t + 1 < nstep) {
            ldst16(Ag + (t + 1) * 32, &As[cur ^ 1][wave * 16][0]);
            ldst16(Bg + (t + 1) * 32, &Bs[cur ^ 1][wave * 16][0]);
        }
        short8 af = *(const short8*)&As[cur][wave * 16 + l16][rchunk];
#pragma unroll
        for (int nt = 0; nt < 4; nt++) {
            short8 bf = *(const short8*)&Bs[cur][nt * 16 + l16][rchunk];
            acc[nt] = __builtin_amdgcn_mfma_f32_16x16x32_bf16(af, bf, acc[nt], 0, 0, 0);
        }
        PIPE_BARRIER();
        cur ^= 1;
    }
#pragma unroll
    for (int nt = 0; nt < 4; nt++) {
        int col = n0 + nt * 16 + l16;
        float bi;
        if (QKV) {
            int bs = (n0 + nt * 16) >> 8;
            const float* bp = bs == 0 ? b0 : (bs == 1 ? b1 : b2);
            bi = bp[col & 255];
        } else {
            bi = b0[col];
        }
#pragma unroll
        for (int r = 0; r < 4; r++) {
            int rowm = m0 + wave * 16 + quad * 4 + r;
            float vv = acc[nt][r] + bi;
            if (GELU) vv = vv * 0.5f * (1.0f + erff(vv * 0.70710678118f));
            if (QKV) {
                int bs = col >> 8;
                int c = col & 255, hh = c >> 4, d = c & 15;
                int bb = rowm / 320, j = rowm - bb * 320;
                size_t plane = (size_t)hh * (M * DK) + (size_t)bb * (TOTAL * DK);
                if (bs == 0) {
                    C[plane + (size_t)j * DK + d] = f2b(vv);
                } else if (bs == 1) {
                    int off = (((j >> 4) * 2 + (d >> 3)) * 16 + (j & 15)) * 8 + (d & 7);
                    C[(size_t)M * DM + plane + off] = f2b(vv);
                } else {
                    int off = ((j >> 5) * 4 + ((j & 15) >> 2)) * 128 +
                              (((j >> 4) & 1) << 2) + (j & 3) + d * 8;
                    C2[plane + off] = f2b(vv);
                }
            } else {
                C[(size_t)rowm * N + col] = f2b(vv);
            }
        }
    }
}

// ---------------- GEMM(16x256) + bias + residual(ures) + LayerNorm -> uout ----------------
__global__ __launch_bounds__(256) void k_gemm_ln16(const ushort* __restrict__ A,
                                                   const ushort* __restrict__ Wt,
                                                   const float* __restrict__ bias,
                                                   const float* __restrict__ ls,
                                                   const float* __restrict__ lb,
                                                   const ushort* __restrict__ ures,
                                                   ushort* __restrict__ uout, int K) {
    __shared__ ushort As[2][16][32];
    __shared__ ushort Bs[2][256][32];
    __shared__ float ps1[16][4], ps2[16][4];
    int tid = threadIdx.x;
    int wave = tid >> 6, lane = tid & 63;
    int quad = lane >> 4, l16 = lane & 15;
    int m0 = blockIdx.x * 16;

    f32x4 acc[4];
#pragma unroll
    for (int nt = 0; nt < 4; nt++) acc[nt] = (f32x4){0.f, 0.f, 0.f, 0.f};

    int brow = wave * 16 + (lane >> 2);
    int bc_swz = (lane & 3) ^ ((brow >> 1) & 3);
    const ushort* Bg0 = &Wt[(size_t)brow * K + bc_swz * 8];
    int ar = lane >> 2;
    int ac = (lane & 3) ^ ((ar >> 1) & 3);
    const ushort* Ag = &A[(size_t)(m0 + ar) * K + ac * 8];
    int rchunk = (quad ^ ((l16 >> 1) & 3)) * 8;

    if (tid < 64) ldst16(Ag, &As[0][0][0]);
#pragma unroll
    for (int i = 0; i < 4; i++)
        ldst16(Bg0 + (size_t)i * 64 * K, &Bs[0][i * 64 + wave * 16][0]);
    PIPE_BARRIER();

    int nstep = K >> 5;
    int cur = 0;
    for (int t = 0; t < nstep; t++) {
        if (t + 1 < nstep) {
            if (tid < 64) ldst16(Ag + (t + 1) * 32, &As[cur ^ 1][0][0]);
#pragma unroll
            for (int i = 0; i < 4; i++)
                ldst16(Bg0 + (size_t)i * 64 * K + (t + 1) * 32, &Bs[cur ^ 1][i * 64 + wave * 16][0]);
        }
        short8 af = *(const short8*)&As[cur][l16][rchunk];
#pragma unroll
        for (int nt = 0; nt < 4; nt++) {
            short8 bf = *(const short8*)&Bs[cur][wave * 64 + nt * 16 + l16][rchunk];
            acc[nt] = __builtin_amdgcn_mfma_f32_16x16x32_bf16(af, bf, acc[nt], 0, 0, 0);
        }
        PIPE_BARRIER();
        cur ^= 1;
    }
    float xv[4][4];
#pragma unroll
    for (int r = 0; r < 4; r++) {
        int rowg = m0 + quad * 4 + r;
        float s1 = 0.f, s2 = 0.f;
#pragma unroll
        for (int nt = 0; nt < 4; nt++) {
            int col = wave * 64 + nt * 16 + l16;
            float x = acc[nt][r] + bias[col] + bu2f(ures[(size_t)rowg * DM + col]);
            xv[r][nt] = x; s1 += x; s2 += x * x;
        }
        s1 += __shfl_xor(s1, 1); s2 += __shfl_xor(s2, 1);
        s1 += __shfl_xor(s1, 2); s2 += __shfl_xor(s2, 2);
        s1 += __shfl_xor(s1, 4); s2 += __shfl_xor(s2, 4);
        s1 += __shfl_xor(s1, 8); s2 += __shfl_xor(s2, 8);
        if (l16 == 0) { ps1[quad * 4 + r][wave] = s1; ps2[quad * 4 + r][wave] = s2; }
    }
    __syncthreads();
#pragma unroll
    for (int r = 0; r < 4; r++) {
        int rowl = quad * 4 + r, rowg = m0 + rowl;
        float s1 = ps1[rowl][0] + ps1[rowl][1] + ps1[rowl][2] + ps1[rowl][3];
        float s2 = ps2[rowl][0] + ps2[rowl][1] + ps2[rowl][2] + ps2[rowl][3];
        float m = s1 * (1.0f / DM);
        float var = s2 * (1.0f / DM) - m * m;
        float rs = rsqrtf(var + EPS);
#pragma unroll
        for (int nt = 0; nt < 4; nt++) {
            int col = wave * 64 + nt * 16 + l16;
            uout[(size_t)rowg * DM + col] = f2b((xv[r][nt] - m) * rs * ls[col] + lb[col]);
        }
    }
}

// ---------------- FFN half: 16 rows x 2 h-chunks -> f32 partial. grid (320, 2) = 640 blocks ----------------
__global__ __launch_bounds__(256) void k_ffnh(const ushort* __restrict__ u1,
                                              const ushort* __restrict__ F1t,  // [1024][256]
                                              const ushort* __restrict__ F2t,  // [256][1024]
                                              const float* __restrict__ c1v,
                                              float* __restrict__ part) {
    __shared__ __align__(16) ushort Au[16 * 256];   // linear; ldst16-staged w/ pre-swizzled src
    __shared__ ushort Bs[2][256][32];
    __shared__ __align__(16) ushort Hs[16][264];
    int tid = threadIdx.x;
    int wave = tid >> 6, lane = tid & 63;
    int quad = lane >> 4, l16 = lane & 15;
    int m0 = blockIdx.x * 16;
    int half = blockIdx.y;

    int brow = wave * 16 + (lane >> 2);
    int bsw = (lane & 3) ^ ((brow >> 1) & 3);
    int rchunk = (quad ^ ((l16 >> 1) & 3)) * 8;

    // stage Au rows from u1: chunk ci covers rows 2ci..2ci+1 (1KB); lane source pre-swizzled
    {
        int rloc = lane >> 5, k32 = (lane & 31) >> 2, pphys = lane & 3;
#pragma unroll
        for (int s = 0; s < 2; s++) {
            int ci = wave + s * 4;
            int row = 2 * ci + rloc;
            int plog = pphys ^ ((row >> 1) & 3);
            ldst16(&u1[(size_t)(m0 + row) * 256 + k32 * 32 + plog * 8], &Au[ci * 512]);
        }
    }
    PIPE_BARRIER();

    f32x4 acc2[4];
#pragma unroll
    for (int nt = 0; nt < 4; nt++) acc2[nt] = (f32x4){0.f, 0.f, 0.f, 0.f};

    for (int ci = 0; ci < 2; ci++) {
        int c = half * 2 + ci;
        // ---- FFN1 chunk c: h[:, c*256..+255], K=256 ----
        f32x4 acc1[4];
#pragma unroll
        for (int nt = 0; nt < 4; nt++) acc1[nt] = (f32x4){0.f, 0.f, 0.f, 0.f};
        const ushort* Bg1 = &F1t[(size_t)(c * 256 + brow) * 256 + bsw * 8];
#pragma unroll
        for (int i = 0; i < 4; i++) ldst16(Bg1 + (size_t)i * 64 * 256, &Bs[0][i * 64 + wave * 16][0]);
        PIPE_BARRIER();
        int cur = 0;
        for (int t = 0; t < 8; t++) {
            if (t + 1 < 8) {
#pragma unroll
                for (int i = 0; i < 4; i++)
                    ldst16(Bg1 + (size_t)i * 64 * 256 + (t + 1) * 32, &Bs[cur ^ 1][i * 64 + wave * 16][0]);
            }
            short8 af = *(const short8*)&Au[l16 * 256 + t * 32 + rchunk];
#pragma unroll
            for (int nt = 0; nt < 4; nt++) {
                short8 bf = *(const short8*)&Bs[cur][wave * 64 + nt * 16 + l16][rchunk];
                acc1[nt] = __builtin_amdgcn_mfma_f32_16x16x32_bf16(af, bf, acc1[nt], 0, 0, 0);
            }
            PIPE_BARRIER();
            cur ^= 1;
        }
        // gelu -> Hs (chunk-local cols 0..255, swizzled + padded)
#pragma unroll
        for (int nt = 0; nt < 4; nt++) {
            int cc = wave * 64 + nt * 16 + l16;
            float bi = c1v[c * 256 + cc];
            int k32 = cc >> 5, pp = (cc >> 3) & 3, e = cc & 7;
#pragma unroll
            for (int r = 0; r < 4; r++) {
                int row = quad * 4 + r;
                float vv = acc1[nt][r] + bi;
                vv = vv * 0.5f * (1.0f + erff(vv * 0.70710678118f));
                int pphys = pp ^ ((row >> 1) & 3);
                Hs[row][k32 * 32 + pphys * 8 + e] = f2b(vv);
            }
        }
        __syncthreads();
        // ---- FFN2 partial: acc2 += Hs @ F2t[:, c*256..+255], K=256 ----
        const ushort* Bg2 = &F2t[(size_t)brow * 1024 + c * 256 + bsw * 8];
#pragma unroll
        for (int i = 0; i < 4; i++) ldst16(Bg2 + (size_t)i * 64 * 1024, &Bs[0][i * 64 + wave * 16][0]);
        PIPE_BARRIER();
        cur = 0;
        for (int t = 0; t < 8; t++) {
            if (t + 1 < 8) {
#pragma unroll
                for (int i = 0; i < 4; i++)
                    ldst16(Bg2 + (size_t)i * 64 * 1024 + (t + 1) * 32, &Bs[cur ^ 1][i * 64 + wave * 16][0]);
            }
            short8 af = *(const short8*)&Hs[l16][t * 32 + rchunk];
#pragma unroll
            for (int nt = 0; nt < 4; nt++) {
                short8 bf = *(const short8*)&Bs[cur][wave * 64 + nt * 16 + l16][rchunk];
                acc2[nt] = __builtin_amdgcn_mfma_f32_16x16x32_bf16(af, bf, acc2[nt], 0, 0, 0);
            }
            PIPE_BARRIER();
            cur ^= 1;
        }
    }

    // write f32 partials (no bias; added in reduce)
#pragma unroll
    for (int nt = 0; nt < 4; nt++) {
        int col = wave * 64 + nt * 16 + l16;
#pragma unroll
        for (int r = 0; r < 4; r++) {
            int rowg = m0 + quad * 4 + r;
            part[((size_t)half * M + rowg) * 256 + col] = acc2[nt][r];
        }
    }
}

// ---------------- sum partials + c2 + residual(u1) + LN2 -> u. 320 blocks ----------------
__global__ __launch_bounds__(256) void k_ln2red(const float* __restrict__ part,
                                                const float* __restrict__ c2v,
                                                const ushort* __restrict__ u1,
                                                const float* __restrict__ ls,
                                                const float* __restrict__ lb,
                                                ushort* __restrict__ u) {
    int tid = threadIdx.x;
    int wave = tid >> 6, lane = tid & 63;
    int m0 = blockIdx.x * 16;
#pragma unroll
    for (int r = 0; r < 4; r++) {
        int row = m0 + wave * 4 + r;
        f32x4 a = *(const f32x4*)&part[(size_t)row * 256 + lane * 4];
        f32x4 b = *(const f32x4*)&part[(size_t)(M + row) * 256 + lane * 4];
        us4 ur = *(const us4*)&u1[(size_t)row * 256 + lane * 4];
        float x[4];
        float s1 = 0.f, s2 = 0.f;
#pragma unroll
        for (int j = 0; j < 4; j++) {
            x[j] = a[j] + b[j] + c2v[lane * 4 + j] + bu2f(ur[j]);
            s1 += x[j]; s2 += x[j] * x[j];
        }
#pragma unroll
        for (int off = 1; off < 64; off <<= 1) {
            s1 += __shfl_xor(s1, off);
            s2 += __shfl_xor(s2, off);
        }
        float m = s1 * (1.0f / DM);
        float var = s2 * (1.0f / DM) - m * m;
        float rs = rsqrtf(var + EPS);
        us4 o;
#pragma unroll
        for (int j = 0; j < 4; j++)
            o[j] = f2b((x[j] - m) * rs * ls[lane * 4 + j] + lb[lane * 4 + j]);
        *(us4*)&u[(size_t)row * 256 + lane * 4] = o;
    }
}

// ---------------- attention: all-DMA staging (pre-permuted K/V), ONE barrier ----------------
__global__ __launch_bounds__(256, 3) void k_attn(const ushort* __restrict__ qk, const ushort* __restrict__ vm,
                                                 ushort* __restrict__ ao, int nj) {
    __shared__ __align__(16) ushort sh[25600];
    int bh = blockIdx.x, b = bh >> 4, h = bh & 15;
    int i0 = blockIdx.y * 64;
    int t = threadIdx.x, wave = t >> 6, lane = t & 63, quad = lane >> 4, l16 = lane & 15;
    const short8 zero8 = (short8){0, 0, 0, 0, 0, 0, 0, 0};
    size_t hplane = (size_t)h * (M * DK) + (size_t)b * (TOTAL * DK);

    int nchunks = (nj + 1) * 10;
    for (int c = wave; c < nchunks; c += 4) {
        int s = c / 10, cc = c - s * 10;
        const ushort* src = (s < nj)
            ? qk + (size_t)(2 * s + 1) * (M * DM) + hplane + cc * 512
            : vm + hplane + cc * 512;
        int dstbase = (s < nj ? s * 5120 : 20480) + cc * 512;
        ldst16(src + lane * 8, &sh[dstbase]);
    }
    short8 qfr[4] = { zero8, zero8, zero8, zero8 };
    int qrow = i0 + wave * 16 + l16;
#pragma unroll
    for (int jl = 0; jl < 4; jl++)
        if (jl < nj && quad < 2)
            qfr[jl] = *(const short8*)&qk[(size_t)(2 * jl) * (M * DM) + hplane +
                                          (size_t)qrow * DK + quad * 8];
    PIPE_BARRIER();

    f32x4 acc[20];
#pragma unroll
    for (int nt = 0; nt < 20; nt++) acc[nt] = (f32x4){0.f, 0.f, 0.f, 0.f};

    __builtin_amdgcn_s_setprio(1);
#pragma unroll
    for (int jl = 0; jl < 4; jl++) {
        if (jl < nj) {
            int kb = jl * 5120;
#pragma unroll
            for (int nt = 0; nt < 20; nt++) {
                short8 kf = *(const short8*)&sh[kb + ((nt * 2 + (quad & 1)) * 16 + l16) * 8];
                acc[nt] = __builtin_amdgcn_mfma_f32_16x16x32_bf16(kf, qfr[jl], acc[nt], 0, 0, 0);
            }
        }
    }
    __builtin_amdgcn_s_setprio(0);

    float mx = -1e30f;
#pragma unroll
    for (int nt = 0; nt < 20; nt++)
#pragma unroll
        for (int r = 0; r < 4; r++) { acc[nt][r] *= SCALE; mx = fmaxf(mx, acc[nt][r]); }
    mx = fmaxf(mx, __shfl_xor(mx, 16));
    mx = fmaxf(mx, __shfl_xor(mx, 32));
    float sum = 0.f;
#pragma unroll
    for (int nt = 0; nt < 20; nt++)
#pragma unroll
        for (int r = 0; r < 4; r++) { acc[nt][r] = __expf(acc[nt][r] - mx); sum += acc[nt][r]; }
    sum += __shfl_xor(sum, 16);
    sum += __shfl_xor(sum, 32);
    float inv = 1.f / sum;
#pragma unroll
    for (int nt = 0; nt < 20; nt++)
#pragma unroll
        for (int r = 0; r < 4; r++) acc[nt][r] *= inv;

    f32x4 oacc = (f32x4){0.f, 0.f, 0.f, 0.f};
    __builtin_amdgcn_s_setprio(1);
#pragma unroll
    for (int jt2 = 0; jt2 < 10; jt2++) {
        short8 vt = *(const short8*)&sh[20480 + ((jt2 * 4 + quad) * 16 + l16) * 8];
        union { short8 v; uint u[4]; } pf;
        pf.u[0] = pack2(acc[2 * jt2][0], acc[2 * jt2][1]);
        pf.u[1] = pack2(acc[2 * jt2][2], acc[2 * jt2][3]);
        pf.u[2] = pack2(acc[2 * jt2 + 1][0], acc[2 * jt2 + 1][1]);
        pf.u[3] = pack2(acc[2 * jt2 + 1][2], acc[2 * jt2 + 1][3]);
        oacc = __builtin_amdgcn_mfma_f32_16x16x32_bf16(vt, pf.v, oacc, 0, 0, 0);
    }
    __builtin_amdgcn_s_setprio(0);
    us4 ov4 = (us4){f2b(oacc[0]), f2b(oacc[1]), f2b(oacc[2]), f2b(oacc[3])};
    *(us4*)&ao[((size_t)b * TOTAL + i0 + wave * 16 + l16) * DM + h * DK + quad * 4] = ov4;
}

// ---------------- head GEMM: MFMA split-K, atomic accumulate into pre-initialized out ----------------
__global__ __launch_bounds__(256) void k_head(const ushort* __restrict__ u, const ushort* __restrict__ WhT2,
                                              const float* __restrict__ scalef, float* __restrict__ out) {
    int t0 = blockIdx.x * 16;
    int wave = threadIdx.x >> 6, lane = threadIdx.x & 63;
    int quad = lane >> 4, l16 = lane & 15;
    int chunk = blockIdx.y * 4 + wave;
    int kbeg = chunk * 1024;
    f32x4 acc = (f32x4){0.f, 0.f, 0.f, 0.f};
    const ushort* za = &u[(size_t)l16 * KHEAD + quad * 8];
    const ushort* wb = &WhT2[(size_t)(t0 + l16) * KHEAD + quad * 8];
#pragma unroll 4
    for (int k = kbeg; k < kbeg + 1024; k += 32) {
        short8 af = *(const short8*)&za[k];
        short8 bf = *(const short8*)&wb[k];
        acc = __builtin_amdgcn_mfma_f32_16x16x32_bf16(af, bf, acc, 0, 0, 0);
    }
#pragma unroll
    for (int r = 0; r < 4; r++) {
        int bcr = quad * 4 + r;
        atomicAdd(&out[bcr * TGT + t0 + l16], acc[r] * scalef[bcr]);
    }
}

extern "C" void kernel_launch(void* const* d_in, const int* in_sizes, int n_in,
                              void* d_out, int out_size, void* d_ws, size_t ws_size,
                              hipStream_t stream) {
    const float* z       = (const float*)d_in[0];
    const float* revin_w = (const float*)d_in[1];
    const float* revin_b = (const float*)d_in[2];
    const float* Wf      = (const float*)d_in[3];
    const float* bfv     = (const float*)d_in[4];
    const float* Wc      = (const float*)d_in[5];
    const float* bcv     = (const float*)d_in[6];
    const float* Wpos    = (const float*)d_in[7];
    const float* WQ      = (const float*)d_in[8];
    const float* bQ      = (const float*)d_in[9];
    const float* WK      = (const float*)d_in[10];
    const float* bK      = (const float*)d_in[11];
    const float* WV      = (const float*)d_in[12];
    const float* bV      = (const float*)d_in[13];
    const float* WO      = (const float*)d_in[14];
    const float* bO      = (const float*)d_in[15];
    const float* ln1s    = (const float*)d_in[16];
    const float* ln1b    = (const float*)d_in[17];
    const float* ln2s    = (const float*)d_in[18];
    const float* ln2b    = (const float*)d_in[19];
    const float* F1      = (const float*)d_in[20];
    const float* c1      = (const float*)d_in[21];
    const float* F2      = (const float*)d_in[22];
    const float* c2      = (const float*)d_in[23];
    const float* Wh      = (const float*)d_in[24];
    const float* bh      = (const float*)d_in[25];
    float* out = (float*)d_out;

    char* p = (char*)d_ws;
    float* scalef = (float*)p;   p += 16 * 4;
    p = (char*)(((size_t)p + 255) & ~255ull);
    ushort* u     = (ushort*)p;  p += (size_t)M * DM * 2;
    ushort* u1    = (ushort*)p;  p += (size_t)M * DM * 2;            // LN1 output
    ushort* qkbuf = (ushort*)p;  p += (size_t)NL * 2 * M * DM * 2;   // per-layer [Q,K] head planes
    ushort* vbuf  = (ushort*)p;  p += (size_t)M * DM * 2;            // V head planes (permuted)
    ushort* ax    = (ushort*)p;  p += (size_t)M * DM * 2;
    float* part   = (float*)p;   p += (size_t)2 * M * 256 * 4;       // FFN2 f32 partials
    ushort* Wtqkv = (ushort*)p;  p += (size_t)NL * 768 * 256 * 2;
    ushort* WtO   = (ushort*)p;  p += (size_t)NL * 256 * 256 * 2;
    ushort* Ft1   = (ushort*)p;  p += (size_t)NL * 1024 * 256 * 2;
    ushort* Ft2   = (ushort*)p;  p += (size_t)NL * 256 * 1024 * 2;
    ushort* WhT2  = (ushort*)p;  p += (size_t)TGT * KHEAD * 2;

    k_prep<<<3328, 256, 0, stream>>>(WQ, WK, WV, WO, F1, F2, Wh,
                                     Wtqkv, WtO, Ft1, Ft2, WhT2,
                                     z, revin_w, revin_b,
                                     Wf, bfv, Wc, bcv, Wpos, u,
                                     bh, out, scalef);

    for (int l = 0; l < NL; l++) {
        k_gemm_mfma<0, 1><<<dim3(12, 80), 256, 0, stream>>>(
            u, Wtqkv + (size_t)l * 768 * 256, bQ + l * DM, bK + l * DM, bV + l * DM,
            qkbuf + (size_t)l * 2 * M * DM, vbuf, M, 768, 256);
        k_attn<<<dim3(NB * NH, 5), 256, 0, stream>>>(qkbuf, vbuf, ax, l + 1);
        k_gemm_ln16<<<M / 16, 256, 0, stream>>>(
            ax, WtO + (size_t)l * 65536, bO + l * DM, ln1s + l * DM, ln1b + l * DM,
            u, u1, 256);
        k_ffnh<<<dim3(M / 16, 2), 256, 0, stream>>>(
            u1, Ft1 + (size_t)l * 262144, Ft2 + (size_t)l * 262144, c1 + l * DFF, part);
        k_ln2red<<<M / 16, 256, 0, stream>>>(
            part, c2 + l * DM, u1, ln2s + l * DM, ln2b + l * DM, u);
    }

    k_head<<<dim3(TGT / 16, 20), 256, 0, stream>>>(u, WhT2, scalef, out);
}